// Round 7
// baseline (980.411 us; speedup 1.0000x reference)
//
#include <hip/hip_runtime.h>
#include <hip/hip_bf16.h>
#include <math.h>

#define B_  2
#define N_  384
#define D_  256
#define PD_ 64
#define L_  8
#define H_  8
#define DH_ 32
#define GR  4      // rows per GEMM block
#define IT  8      // attention i-tile
#define RT_ 132    // relcT row stride (129 padded)

// ---------------- prologue: embed+LN, frames/t init, centered relpos, zero ff-target ------------
// grid = M, 256 threads
__global__ void prologue_kernel(const int* __restrict__ tokens, const float* __restrict__ tok_emb,
                                const float* __restrict__ lnw, const float* __restrict__ lnb,
                                const float* __restrict__ relpos,
                                float* __restrict__ x, float* __restrict__ frames,
                                float* __restrict__ tx, float* __restrict__ ty,
                                float* __restrict__ tz,
                                float* __restrict__ relc, float* __restrict__ relcT,
                                float* __restrict__ xz) {
  int row = blockIdx.x;            // b*N + n
  int n = row % N_;
  int d = threadIdx.x;             // 0..255
  __shared__ float rbuf[256];
  __shared__ float smr;
  if (d < 16) frames[row * 16 + d] = (d == 0 || d == 5 || d == 10 || d == 15) ? 1.0f : 0.0f;
  if (d == 16) tx[row] = 0.0f;
  if (d == 17) ty[row] = 0.0f;
  if (d == 18) tz[row] = 0.0f;
  xz[(size_t)row * D_ + d] = 0.0f;          // zero layer-0 ff accumulation target
  // rel row mean (blocks 0..128, wave 3)
  if (row < 129 && d >= 192) {
    int lane = d & 63;
    float s = relpos[row * PD_ + lane];
    #pragma unroll
    for (int off = 32; off >= 1; off >>= 1) s += __shfl_xor(s, off, 64);
    if (lane == 0) smr = s * (1.0f / PD_);
  }
  // embed + pos-enc + LN
  int tok = tokens[row];
  float val = tok_emb[tok * D_ + d];
  int i = d >> 1;
  float dv = expf((float)(2 * i) * (-logf(10000.0f) / (float)D_));
  float ang = (float)n * dv;
  val += (d & 1) ? cosf(ang) : sinf(ang);
  rbuf[d] = val; __syncthreads();          // smr visible after this
  for (int s = 128; s > 0; s >>= 1) { if (d < s) rbuf[d] += rbuf[d + s]; __syncthreads(); }
  float mean = rbuf[0] / D_;
  __syncthreads();
  rbuf[d] = val * val; __syncthreads();
  for (int s = 128; s > 0; s >>= 1) { if (d < s) rbuf[d] += rbuf[d + s]; __syncthreads(); }
  float var = rbuf[0] / D_ - mean * mean;
  float r = rsqrtf(var + 1e-5f);
  x[row * D_ + d] = (val - mean) * r * lnw[d] + lnb[d];
  // centered relpos + transpose
  if (row < 129 && d < PD_) {
    float cv = relpos[row * PD_ + d] - smr;
    relc[row * PD_ + d] = cv;
    relcT[d * RT_ + row] = cv;
  }
}

// ---------------- qkv unit (GR=4, k-chunk 4 x col-tile 64; K transposed) ----------------
__device__ __forceinline__ void qkv_unit(int bid, int tid, const float* __restrict__ x,
                                         const float* __restrict__ Wq, const float* __restrict__ Wk,
                                         const float* __restrict__ Wv,
                                         float* __restrict__ q, float* __restrict__ kt,
                                         float* __restrict__ v, float* sA) {
  int tile = bid & 3;
  int m = (bid >> 2) % 3;
  int r0 = (bid / 12) * GR;
  float* red = sA + GR * D_;       // 1024 floats
  {
    int r = tid >> 6, lane = tid & 63;
    ((float4*)(sA + r * D_))[lane] = ((const float4*)(x + (size_t)(r0 + r) * D_))[lane];
  }
  __syncthreads();
  const float* W = (m == 0) ? Wq : (m == 1) ? Wk : Wv;
  int kc = tid >> 6, c = tid & 63;
  const float* wp = W + (size_t)(kc * 64) * D_ + tile * 64 + c;
  const float* s0 = sA + kc * 64;
  float a0 = 0.f, a1 = 0.f, a2 = 0.f, a3 = 0.f;
  for (int kk = 0; kk < 64; kk += 4) {
    float w0 = wp[(size_t)kk * D_], w1 = wp[(size_t)(kk + 1) * D_];
    float w2 = wp[(size_t)(kk + 2) * D_], w3 = wp[(size_t)(kk + 3) * D_];
    float4 h0 = *(const float4*)(s0 + 0 * D_ + kk);
    float4 h1 = *(const float4*)(s0 + 1 * D_ + kk);
    float4 h2 = *(const float4*)(s0 + 2 * D_ + kk);
    float4 h3 = *(const float4*)(s0 + 3 * D_ + kk);
    a0 = fmaf(h0.x, w0, fmaf(h0.y, w1, fmaf(h0.z, w2, fmaf(h0.w, w3, a0))));
    a1 = fmaf(h1.x, w0, fmaf(h1.y, w1, fmaf(h1.z, w2, fmaf(h1.w, w3, a1))));
    a2 = fmaf(h2.x, w0, fmaf(h2.y, w1, fmaf(h2.z, w2, fmaf(h2.w, w3, a2))));
    a3 = fmaf(h3.x, w0, fmaf(h3.y, w1, fmaf(h3.z, w2, fmaf(h3.w, w3, a3))));
  }
  red[(kc * 4 + 0) * 64 + c] = a0;
  red[(kc * 4 + 1) * 64 + c] = a1;
  red[(kc * 4 + 2) * 64 + c] = a2;
  red[(kc * 4 + 3) * 64 + c] = a3;
  __syncthreads();
  int r = tid >> 6;
  float s = red[(0 * 4 + r) * 64 + c] + red[(1 * 4 + r) * 64 + c]
          + red[(2 * 4 + r) * 64 + c] + red[(3 * 4 + r) * 64 + c];
  int col = tile * 64 + c;
  int row = r0 + r;
  if (m == 1) {
    int b = row / N_, j = row % N_;
    int hh = col >> 5, dd = col & 31;
    kt[((size_t)(b * H_ + hh) * DH_ + dd) * N_ + j] = s;
  } else {
    float* O = (m == 0) ? q : v;
    O[(size_t)row * D_ + col] = s;
  }
}

// ---------------- proj unit: centered relu(x@Wop+bop) -> projc (+transposed); zero zbuf row ----
__device__ __forceinline__ void proj_unit(int row, int tid, const float* __restrict__ x,
                                          const float* __restrict__ Wop, const float* __restrict__ bop,
                                          float* __restrict__ projc, float* __restrict__ projcT,
                                          float* __restrict__ zbuf, float* smem) {
  float* sA  = smem;               // 256
  float* red = smem + 256;         // 256
  zbuf[(size_t)row * D_ + tid] = 0.0f;     // zero next ff accumulation target
  if (tid < 64) ((float4*)sA)[tid] = ((const float4*)(x + (size_t)row * D_))[tid];
  __syncthreads();
  int kc = tid >> 6, c = tid & 63;
  const float* wp = Wop + (kc * 64) * PD_ + c;
  const float* s0 = sA + kc * 64;
  float a0 = 0.f, a1 = 0.f, a2 = 0.f, a3 = 0.f;
  for (int kk = 0; kk < 64; kk += 4) {
    a0 = fmaf(s0[kk],     wp[(kk)     * PD_], a0);
    a1 = fmaf(s0[kk + 1], wp[(kk + 1) * PD_], a1);
    a2 = fmaf(s0[kk + 2], wp[(kk + 2) * PD_], a2);
    a3 = fmaf(s0[kk + 3], wp[(kk + 3) * PD_], a3);
  }
  red[kc * 64 + c] = (a0 + a1) + (a2 + a3);
  __syncthreads();
  if (tid < 64) {
    float acc = fmaxf(bop[tid] + red[tid] + red[64 + tid] + red[128 + tid] + red[192 + tid], 0.0f);
    float s = acc;
    #pragma unroll
    for (int off = 32; off >= 1; off >>= 1) s += __shfl_xor(s, off, 64);
    float cv = acc - s * (1.0f / PD_);
    projc[row * PD_ + tid] = cv;
    projcT[(size_t)tid * (B_ * N_) + row] = cv;
  }
}

// ---------------- standalone qkv (layer 0) ----------------
__global__ void qkv_kernel(const float* __restrict__ x, const float* __restrict__ Wq,
                           const float* __restrict__ Wk, const float* __restrict__ Wv,
                           float* __restrict__ q, float* __restrict__ kt, float* __restrict__ v) {
  __shared__ __align__(16) float smem[2048];
  qkv_unit(blockIdx.x, threadIdx.x, x, Wq, Wk, Wv, q, kt, v, smem);
}

// ---------------- combined proj(l) + qkv(l+1): both read only x ----------------
__global__ void proj_qkv_kernel(const float* __restrict__ x,
                                const float* __restrict__ Wop, const float* __restrict__ bop,
                                float* __restrict__ projc, float* __restrict__ projcT,
                                const float* __restrict__ Wq, const float* __restrict__ Wk,
                                const float* __restrict__ Wv,
                                float* __restrict__ q, float* __restrict__ kt,
                                float* __restrict__ v, float* __restrict__ zbuf) {
  __shared__ __align__(16) float smem[2048];
  int bid = blockIdx.x, tid = threadIdx.x;
  if (bid < B_ * N_) proj_unit(bid, tid, x, Wop, bop, projc, projcT, zbuf, smem);
  else               qkv_unit(bid - B_ * N_, tid, x, Wq, Wk, Wv, q, kt, v, smem);
}

// ---------------- fused FF: T += x + b2 + gelu(ffLN(x)@W1+b1)@W2, x = attnLN(S + bo) -----------
// grid = (M/GR)*8 = 1536, 256 threads. S holds x_resid + ao@Wo (attn-accumulated).
// Each block owns a 128-wide f-slice (split-K of W2); atomically accumulates into T (pre-zeroed).
__global__ void ff_fused_kernel(const float* __restrict__ S, const float* __restrict__ bo,
                                const float* __restrict__ alnw, const float* __restrict__ alnb,
                                const float* __restrict__ flnw, const float* __restrict__ flnb,
                                const float* __restrict__ W1, const float* __restrict__ b1,
                                const float* __restrict__ W2, const float* __restrict__ b2v,
                                float* __restrict__ T) {
  int bid = blockIdx.x;
  int tile = bid & 7;              // 128 f-cols each
  int r0 = (bid >> 3) * GR;
  int tid = threadIdx.x;
  __shared__ __align__(16) float sA[GR * D_];       // ff-LN'd h rows (4 KB)
  __shared__ __align__(16) float sX[GR * D_];       // attn-LN'd x rows (4 KB)
  __shared__ float red[2 * GR * 128];               // split-k partials (4 KB)
  __shared__ __align__(16) float sF[128 * 4];       // f tile [k][r] (2 KB)
  {
    int r = tid >> 6, lane = tid & 63;
    float4 v = ((const float4*)(S + (size_t)(r0 + r) * D_))[lane];
    float4 bo4 = ((const float4*)bo)[lane];
    v.x += bo4.x; v.y += bo4.y; v.z += bo4.z; v.w += bo4.w;
    // attn LN
    float s = v.x + v.y + v.z + v.w;
    float s2 = v.x * v.x + v.y * v.y + v.z * v.z + v.w * v.w;
    #pragma unroll
    for (int off = 32; off >= 1; off >>= 1) {
      s  += __shfl_xor(s, off, 64);
      s2 += __shfl_xor(s2, off, 64);
    }
    float mean = s * (1.0f / D_);
    float var = s2 * (1.0f / D_) - mean * mean;
    float rin = rsqrtf(var + 1e-5f);
    float4 aw = ((const float4*)alnw)[lane];
    float4 ab = ((const float4*)alnb)[lane];
    float4 x4;
    x4.x = (v.x - mean) * rin * aw.x + ab.x;
    x4.y = (v.y - mean) * rin * aw.y + ab.y;
    x4.z = (v.z - mean) * rin * aw.z + ab.z;
    x4.w = (v.w - mean) * rin * aw.w + ab.w;
    ((float4*)(sX + r * D_))[lane] = x4;
    // ff LN
    float t = x4.x + x4.y + x4.z + x4.w;
    float t2 = x4.x * x4.x + x4.y * x4.y + x4.z * x4.z + x4.w * x4.w;
    #pragma unroll
    for (int off = 32; off >= 1; off >>= 1) {
      t  += __shfl_xor(t, off, 64);
      t2 += __shfl_xor(t2, off, 64);
    }
    float mean2 = t * (1.0f / D_);
    float var2 = t2 * (1.0f / D_) - mean2 * mean2;
    float rin2 = rsqrtf(var2 + 1e-5f);
    float4 fw = ((const float4*)flnw)[lane];
    float4 fb = ((const float4*)flnb)[lane];
    float4 h4;
    h4.x = (x4.x - mean2) * rin2 * fw.x + fb.x;
    h4.y = (x4.y - mean2) * rin2 * fw.y + fb.y;
    h4.z = (x4.z - mean2) * rin2 * fw.z + fb.z;
    h4.w = (x4.w - mean2) * rin2 * fw.w + fb.w;
    ((float4*)(sA + r * D_))[lane] = h4;
  }
  __syncthreads();
  // ---- W1 GEMM: 2 k-chunks x 128 cols ----
  {
    int kc = tid >> 7, c = tid & 127;
    int col = tile * 128 + c;
    const float* wp = W1 + (size_t)(kc * 128) * 1024 + col;
    const float* s0 = sA + kc * 128;
    float a0 = 0.f, a1 = 0.f, a2 = 0.f, a3 = 0.f;
    for (int kk = 0; kk < 128; kk += 4) {
      float w0 = wp[(size_t)kk * 1024], w1 = wp[(size_t)(kk + 1) * 1024];
      float w2 = wp[(size_t)(kk + 2) * 1024], w3 = wp[(size_t)(kk + 3) * 1024];
      float4 h0 = *(const float4*)(s0 + 0 * D_ + kk);
      float4 h1 = *(const float4*)(s0 + 1 * D_ + kk);
      float4 h2 = *(const float4*)(s0 + 2 * D_ + kk);
      float4 h3 = *(const float4*)(s0 + 3 * D_ + kk);
      a0 = fmaf(h0.x, w0, fmaf(h0.y, w1, fmaf(h0.z, w2, fmaf(h0.w, w3, a0))));
      a1 = fmaf(h1.x, w0, fmaf(h1.y, w1, fmaf(h1.z, w2, fmaf(h1.w, w3, a1))));
      a2 = fmaf(h2.x, w0, fmaf(h2.y, w1, fmaf(h2.z, w2, fmaf(h2.w, w3, a2))));
      a3 = fmaf(h3.x, w0, fmaf(h3.y, w1, fmaf(h3.z, w2, fmaf(h3.w, w3, a3))));
    }
    red[(kc * 4 + 0) * 128 + c] = a0;
    red[(kc * 4 + 1) * 128 + c] = a1;
    red[(kc * 4 + 2) * 128 + c] = a2;
    red[(kc * 4 + 3) * 128 + c] = a3;
  }
  __syncthreads();
  // ---- gelu, f tile to LDS [k][r] ----
  {
    int rA = tid >> 7, c = tid & 127;
    int col = tile * 128 + c;
    #pragma unroll
    for (int p = 0; p < 2; p++) {
      int r = rA + p * 2;
      float s = red[(0 * 4 + r) * 128 + c] + red[(1 * 4 + r) * 128 + c] + b1[col];
      s = 0.5f * s * (1.0f + erff(s * 0.7071067811865475f));
      sF[c * 4 + r] = s;
    }
  }
  __syncthreads();
  // ---- W2 partial (128 k-slice x 256 out-cols), atomic accumulate ----
  {
    const float* w2p = W2 + (size_t)(tile * 128) * D_ + tid;
    float o0 = 0.f, o1 = 0.f, o2 = 0.f, o3 = 0.f;
    #pragma unroll 8
    for (int k = 0; k < 128; k++) {
      float w = w2p[(size_t)k * D_];
      float4 f4 = *(const float4*)(sF + k * 4);
      o0 = fmaf(f4.x, w, o0); o1 = fmaf(f4.y, w, o1);
      o2 = fmaf(f4.z, w, o2); o3 = fmaf(f4.w, w, o3);
    }
    if (tile == 0) {
      float bb2 = b2v[tid];
      o0 += sX[0 * D_ + tid] + bb2;
      o1 += sX[1 * D_ + tid] + bb2;
      o2 += sX[2 * D_ + tid] + bb2;
      o3 += sX[3 * D_ + tid] + bb2;
    }
    atomicAdd(&T[(size_t)(r0 + 0) * D_ + tid], o0);
    atomicAdd(&T[(size_t)(r0 + 1) * D_ + tid], o1);
    atomicAdd(&T[(size_t)(r0 + 2) * D_ + tid], o2);
    atomicAdd(&T[(size_t)(r0 + 3) * D_ + tid], o3);
  }
}

// ---------------- attention (de-staged: K/V direct from L2) + fused Wo partial ------------------
// grid = B*H*(N/IT) = 768, 256 threads. Only 2 barriers; LDS = sS (12 KB) + sAO (1 KB).
// S holds the residual stream x; each block atomically adds its head's Wo partial.
__global__ void attn_kernel(const float* __restrict__ Q, const float* __restrict__ KT,
                            const float* __restrict__ V,
                            const float* __restrict__ tx, const float* __restrict__ ty,
                            const float* __restrict__ tz,
                            const float* __restrict__ Wo, float* __restrict__ S) {
  const int TILES = N_ / IT;       // 48
  int bid = blockIdx.x;
  int it = bid % TILES;
  int h  = (bid / TILES) % H_;
  int b  = bid / (TILES * H_);
  int i0 = it * IT;
  int tid = threadIdx.x;
  int wave = tid >> 6, lane = tid & 63;

  __shared__ __align__(16) float sS[IT][N_];
  __shared__ __align__(16) float sAO[IT * DH_];

  // direct Q-hoist: wave w owns rows 2w, 2w+1 (broadcast loads, L1-resident)
  const float* q0p = Q + ((size_t)(b * N_ + i0 + wave * 2 + 0)) * D_ + h * DH_;
  const float* q1p = Q + ((size_t)(b * N_ + i0 + wave * 2 + 1)) * D_ + h * DH_;
  float4 q0r[8], q1r[8];
  #pragma unroll
  for (int t = 0; t < 8; t++) {
    q0r[t] = ((const float4*)q0p)[t];
    q1r[t] = ((const float4*)q1p)[t];
  }
  int rrow = b * N_ + i0 + wave * 2;
  float t0x = tx[rrow],     t0y = ty[rrow],     t0z = tz[rrow];
  float t1x = tx[rrow + 1], t1y = ty[rrow + 1], t1z = tz[rrow + 1];

  const float* ktb = KT + (size_t)(b * H_ + h) * DH_ * N_;
  const float* txb = tx + b * N_;
  const float* tyb = ty + b * N_;
  const float* tzb = tz + b * N_;

  // ---- QK^T + dist bias -> sS (own-lane writes only; no barriers) ----
  for (int jc = 0; jc < N_; jc += 64) {
    int jj = jc + lane;
    float tjx = txb[jj], tjy = tyb[jj], tjz = tzb[jj];
    const float* kp = ktb + jj;
    float a0 = 0.f, a1 = 0.f;
    #pragma unroll
    for (int t = 0; t < 8; t++) {
      float k0 = kp[(size_t)(4 * t + 0) * N_];
      float k1 = kp[(size_t)(4 * t + 1) * N_];
      float k2 = kp[(size_t)(4 * t + 2) * N_];
      float k3 = kp[(size_t)(4 * t + 3) * N_];
      float4 qa = q0r[t], qb = q1r[t];
      a0 = fmaf(qa.x, k0, fmaf(qa.y, k1, fmaf(qa.z, k2, fmaf(qa.w, k3, a0))));
      a1 = fmaf(qb.x, k0, fmaf(qb.y, k1, fmaf(qb.z, k2, fmaf(qb.w, k3, a1))));
    }
    float dx0 = t0x - tjx, dy0 = t0y - tjy, dz0 = t0z - tjz;
    float dx1 = t1x - tjx, dy1 = t1y - tjy, dz1 = t1z - tjz;
    sS[wave * 2 + 0][jj] = a0 * 0.17677669529663689f - (dx0 * dx0 + dy0 * dy0 + dz0 * dz0);
    sS[wave * 2 + 1][jj] = a1 * 0.17677669529663689f - (dx1 * dx1 + dy1 * dy1 + dz1 * dz1);
  }

  // ---- softmax per wave (own-lane sS reads/writes + shuffles; sums kept in registers) ----
  float ps0 = 0.f, ps1 = 0.f;
  #pragma unroll
  for (int s = 0; s < 2; s++) {
    int ii = wave * 2 + s;
    float vrow[6];
    float m = -1e30f;
    #pragma unroll
    for (int t = 0; t < 6; t++) { vrow[t] = sS[ii][t * 64 + lane]; m = fmaxf(m, vrow[t]); }
    #pragma unroll
    for (int off = 32; off >= 1; off >>= 1) m = fmaxf(m, __shfl_xor(m, off, 64));
    float ps = 0.f;
    #pragma unroll
    for (int t = 0; t < 6; t++) {
      float e = expf(vrow[t] - m);
      sS[ii][t * 64 + lane] = e;
      ps += e;
    }
    #pragma unroll
    for (int off = 32; off >= 1; off >>= 1) ps += __shfl_xor(ps, off, 64);
    if (s == 0) ps0 = ps; else ps1 = ps;
  }
  __syncthreads();                 // barrier 1: sS e-values read cross-lane in PV

  // ---- PV: V direct from global (L1/L2-resident; 128B broadcast groups) ----
  int ii = tid >> 5, dd = tid & 31;
  const float* vp = V + (size_t)b * N_ * D_ + h * DH_ + dd;
  const float* srow = sS[ii];
  float o0 = 0.f, o1 = 0.f;
  for (int jc = 0; jc < N_; jc += 64) {
    #pragma unroll
    for (int jj = 0; jj < 64; jj += 4) {
      float4 sv = *(const float4*)(srow + jc + jj);
      o0 = fmaf(sv.x, vp[(size_t)(jc + jj + 0) * D_], o0);
      o1 = fmaf(sv.y, vp[(size_t)(jc + jj + 1) * D_], o1);
      o0 = fmaf(sv.z, vp[(size_t)(jc + jj + 2) * D_], o0);
      o1 = fmaf(sv.w, vp[(size_t)(jc + jj + 3) * D_], o1);
    }
  }
  float pinv = 1.0f / ((lane < 32) ? ps0 : ps1);   // row ii's sum (wave-uniform ps0/ps1)
  sAO[tid] = (o0 + o1) * pinv;     // sAO[ii*32+dd] == sAO[tid]
  __syncthreads();                 // barrier 2: ao tile read cross-wave in Wo phase

  // ---- fused Wo partial: head-slice GEMM + atomics ----
  {
    const float* wo = Wo + (size_t)(h * DH_) * D_ + tid;   // col = tid
    float acc[8];
    #pragma unroll
    for (int r = 0; r < 8; r++) acc[r] = 0.f;
    for (int k = 0; k < DH_; k += 4) {
      float w0 = wo[(size_t)(k + 0) * D_];
      float w1 = wo[(size_t)(k + 1) * D_];
      float w2 = wo[(size_t)(k + 2) * D_];
      float w3 = wo[(size_t)(k + 3) * D_];
      #pragma unroll
      for (int r = 0; r < 8; r++) {
        float4 a4 = *(const float4*)(sAO + r * DH_ + k);
        acc[r] = fmaf(a4.x, w0, fmaf(a4.y, w1, fmaf(a4.z, w2, fmaf(a4.w, w3, acc[r]))));
      }
    }
    float* Sb = S + ((size_t)(b * N_ + i0)) * D_ + tid;
    #pragma unroll
    for (int r = 0; r < 8; r++) atomicAdd(Sb + (size_t)r * D_, acc[r]);
  }
}

// ---------------- fused pair LN-mean + head (shuffle-free pair phase) ----------------
// grid = M, 256 threads
__global__ void pair_head_kernel(const float* __restrict__ projc, const float* __restrict__ projcT,
                                 const float* __restrict__ relc, const float* __restrict__ relcT,
                                 const float* __restrict__ lnw, const float* __restrict__ lnb,
                                 const float* __restrict__ x,
                                 const float* __restrict__ Wf1, const float* __restrict__ bWf1,
                                 const float* __restrict__ Wf2, const float* __restrict__ bWf2,
                                 float* __restrict__ frames, float* __restrict__ tx,
                                 float* __restrict__ ty, float* __restrict__ tz) {
  const int M = B_ * N_;
  int row = blockIdx.x;            // b*N + i
  int b = row / N_;
  int i = row % N_;
  int tid = threadIdx.x;           // 256 = 4 waves
  int lane = tid & 63;
  int wave = tid >> 6;
  __shared__ float svpi[PD_];
  __shared__ float sr[N_];         // rinv per j
  __shared__ float red[4][PD_];
  __shared__ float sfeat[320];
  __shared__ float fred[2][128];
  __shared__ float sg[128];
  __shared__ float sraw[9];

  if (tid < PD_) svpi[tid] = projc[row * PD_ + tid];
  if (tid < D_) sfeat[tid] = x[(size_t)row * D_ + tid];
  __syncthreads();

  // ---- pass A: rinv[j] via thread-per-j (coalesced transposed reads, no shuffles) ----
  {
    int jA = tid;                  // 0..255
    int raA = jA - i; raA = raA < -64 ? -64 : (raA > 64 ? 64 : raA); raA += 64;
    const float* pA = projcT + b * N_ + jA;
    const float* rA = relcT + raA;
    float s2A = 0.f;
    #pragma unroll 8
    for (int c = 0; c < PD_; c++) {
      float dA = svpi[c] + pA[(size_t)c * M] + rA[c * RT_];
      s2A = fmaf(dA, dA, s2A);
    }
    sr[jA] = rsqrtf(s2A * (1.0f / PD_) + 1e-5f);
    if (tid < 128) {
      int jB = tid + 256;          // 256..383
      int raB = jB - i; raB = raB < -64 ? -64 : (raB > 64 ? 64 : raB); raB += 64;
      const float* pB = projcT + b * N_ + jB;
      const float* rB = relcT + raB;
      float s2B = 0.f;
      #pragma unroll 8
      for (int c = 0; c < PD_; c++) {
        float dB = svpi[c] + pB[(size_t)c * M] + rB[c * RT_];
        s2B = fmaf(dB, dB, s2B);
      }
      sr[jB] = rsqrtf(s2B * (1.0f / PD_) + 1e-5f);
    }
  }
  __syncthreads();

  // ---- pass B: per-channel accumulation (row-major coalesced, no shuffles) ----
  {
    float vpl = svpi[lane];
    const float* pb = projc + (size_t)b * N_ * PD_;
    float acc = 0.0f;
    for (int j = wave * 2; j < N_; j += 8) {
      int ja = j, jb = j + 1;
      int ra = ja - i; ra = ra < -64 ? -64 : (ra > 64 ? 64 : ra); ra += 64;
      int rb = jb - i; rb = rb < -64 ? -64 : (rb > 64 ? 64 : rb); rb += 64;
      float da = vpl + pb[ja * PD_ + lane] + relc[ra * PD_ + lane];
      float db = vpl + pb[jb * PD_ + lane] + relc[rb * PD_ + lane];
      acc = fmaf(da, sr[ja], fmaf(db, sr[jb], acc));
    }
    red[wave][lane] = acc;
  }
  __syncthreads();
  if (wave == 0) {
    float s = red[0][lane] + red[1][lane] + red[2][lane] + red[3][lane];
    sfeat[D_ + lane] = lnb[lane] + s * lnw[lane] * (1.0f / N_);
  }
  __syncthreads();

  // ---- fc1 silu (320 -> 128), 2 k-chunks x 128 cols ----
  int kc = tid >> 7, c = tid & 127;
  int koff = kc * 160;
  const float* wp = Wf1 + (size_t)koff * 128 + c;
  const float* s0 = sfeat + koff;
  float a0 = 0.f, a1 = 0.f, a2 = 0.f, a3 = 0.f;
  for (int kk = 0; kk < 160; kk += 4) {
    a0 = fmaf(s0[kk],     wp[(size_t)kk * 128],       a0);
    a1 = fmaf(s0[kk + 1], wp[(size_t)(kk + 1) * 128], a1);
    a2 = fmaf(s0[kk + 2], wp[(size_t)(kk + 2) * 128], a2);
    a3 = fmaf(s0[kk + 3], wp[(size_t)(kk + 3) * 128], a3);
  }
  fred[kc][c] = (a0 + a1) + (a2 + a3);
  __syncthreads();
  if (tid < 128) {
    float g = fred[0][tid] + fred[1][tid] + bWf1[tid];
    sg[tid] = g / (1.0f + expf(-g));
  }
  __syncthreads();

  // ---- fc2 (128 -> 9), rot6d, frame write ----
  if (tid < 9) {
    float b0 = 0.f, b1v = 0.f;
    for (int kk = 0; kk < 128; kk += 2) {
      b0  = fmaf(sg[kk],     Wf2[(kk)     * 9 + tid], b0);
      b1v = fmaf(sg[kk + 1], Wf2[(kk + 1) * 9 + tid], b1v);
    }
    sraw[tid] = bWf2[tid] + b0 + b1v;
  }
  __syncthreads();
  if (tid == 0) {
    float a1x = sraw[0], a1y = sraw[1], a1z = sraw[2];
    float a2x = sraw[3], a2y = sraw[4], a2z = sraw[5];
    float n1 = sqrtf(a1x * a1x + a1y * a1y + a1z * a1z + 1e-8f);
    float b1x = a1x / n1, b1y = a1y / n1, b1z = a1z / n1;
    float dp = b1x * a2x + b1y * a2y + b1z * a2z;
    float px = a2x - dp * b1x, py = a2y - dp * b1y, pz = a2z - dp * b1z;
    float n2 = sqrtf(px * px + py * py + pz * pz + 1e-8f);
    float b2x = px / n2, b2y = py / n2, b2z = pz / n2;
    float b3x = b1y * b2z - b1z * b2y;
    float b3y = b1z * b2x - b1x * b2z;
    float b3z = b1x * b2y - b1y * b2x;
    float* f = frames + row * 16;
    f[0]  = b1x; f[1]  = b1y; f[2]  = b1z; f[3]  = sraw[6];
    f[4]  = b2x; f[5]  = b2y; f[6]  = b2z; f[7]  = sraw[7];
    f[8]  = b3x; f[9]  = b3y; f[10] = b3z; f[11] = sraw[8];
    f[12] = 0.0f; f[13] = 0.0f; f[14] = 0.0f; f[15] = 1.0f;
    tx[row] = sraw[6];
    ty[row] = sraw[7];
    tz[row] = sraw[8];
  }
}

// ---------------- output ----------------
__global__ void write_out_kernel(const float* __restrict__ frames, const float* __restrict__ x,
                                 float* __restrict__ out) {
  int i = blockIdx.x * 256 + threadIdx.x;
  const int nf = B_ * N_ * 16;
  const int total = nf + B_ * N_ * D_;
  if (i < nf) out[i] = frames[i];
  else if (i < total) out[i] = x[i - nf];
}

extern "C" void kernel_launch(void* const* d_in, const int* in_sizes, int n_in,
                              void* d_out, int out_size, void* d_ws, size_t ws_size,
                              hipStream_t stream) {
  const int*   tokens    = (const int*)  d_in[0];
  const float* tok_emb   = (const float*)d_in[1];
  const float* emb_ln_w  = (const float*)d_in[2];
  const float* emb_ln_b  = (const float*)d_in[3];
  const float* Wq        = (const float*)d_in[4];
  const float* Wk        = (const float*)d_in[5];
  const float* Wv        = (const float*)d_in[6];
  const float* Wo        = (const float*)d_in[7];
  const float* bo        = (const float*)d_in[8];
  const float* attn_ln_w = (const float*)d_in[9];
  const float* attn_ln_b = (const float*)d_in[10];
  const float* ff_ln_w   = (const float*)d_in[11];
  const float* ff_ln_b   = (const float*)d_in[12];
  const float* W1        = (const float*)d_in[13];
  const float* b1        = (const float*)d_in[14];
  const float* W2        = (const float*)d_in[15];
  const float* b2        = (const float*)d_in[16];
  const float* Wop       = (const float*)d_in[17];
  const float* bop       = (const float*)d_in[18];
  const float* relpos    = (const float*)d_in[19];
  const float* pair_ln_w = (const float*)d_in[20];
  const float* pair_ln_b = (const float*)d_in[21];
  const float* Wf1       = (const float*)d_in[22];
  const float* bWf1      = (const float*)d_in[23];
  const float* Wf2       = (const float*)d_in[24];
  const float* bWf2      = (const float*)d_in[25];

  const int M = B_ * N_;           // 768
  const int XE = M * D_;           // 196608
  float* ws     = (float*)d_ws;
  float* frames = ws;                      // 12288
  float* projc  = frames + M * 16;         // 49152
  float* projcT = projc  + M * PD_;        // 49152
  float* relc   = projcT + M * PD_;        // 8256 (pad 8320)
  float* relcT  = relc   + 8320;           // 64*132 = 8448
  float* tx     = relcT  + 8448;           // 768
  float* ty     = tx     + M;              // 768
  float* tz     = ty     + M;              // 768
  float* xA     = tz     + M;              // XE  (state ping)
  float* xB     = xA + XE;                 // XE  (state pong)
  float* q      = xB + XE;                 // XE
  float* kt     = q  + XE;                 // XE (K transposed [b,h,d,j])
  float* v      = kt + XE;                 // XE

  prologue_kernel<<<M, 256, 0, stream>>>(tokens, tok_emb, emb_ln_w, emb_ln_b, relpos,
                                         xA, frames, tx, ty, tz, relc, relcT, xB);
  qkv_kernel<<<(M / GR) * 12, 256, 0, stream>>>(xA, Wq, Wk, Wv, q, kt, v);

  for (int l = 0; l < L_; l++) {
    float* Sin  = (l & 1) ? xB : xA;       // holds x_l; attn accumulates ao@Wo into it
    float* Sout = (l & 1) ? xA : xB;       // pre-zeroed; ff accumulates new state
    attn_kernel<<<B_ * H_ * (N_ / IT), 256, 0, stream>>>(
        q, kt, v, tx, ty, tz, Wo + (size_t)l * D_ * D_, Sin);
    ff_fused_kernel<<<(M / GR) * 8, 256, 0, stream>>>(
        Sin, bo + l * D_,
        attn_ln_w + l * D_, attn_ln_b + l * D_,
        ff_ln_w + l * D_, ff_ln_b + l * D_,
        W1 + (size_t)l * D_ * 1024, b1 + l * 1024,
        W2 + (size_t)l * 1024 * D_, b2 + l * D_, Sout);
    if (l < L_ - 1) {
      int lq = l + 1;
      proj_qkv_kernel<<<M + (M / GR) * 12, 256, 0, stream>>>(
          Sout, Wop, bop, projc, projcT,
          Wq + (size_t)lq * D_ * D_, Wk + (size_t)lq * D_ * D_, Wv + (size_t)lq * D_ * D_,
          q, kt, v, Sin);
    } else {
      proj_qkv_kernel<<<M, 256, 0, stream>>>(Sout, Wop, bop, projc, projcT,
                                             Wq, Wk, Wv, q, kt, v, Sin);
    }
    pair_head_kernel<<<M, 256, 0, stream>>>(projc, projcT, relc, relcT, pair_ln_w, pair_ln_b,
                                            Sout, Wf1, bWf1, Wf2, bWf2, frames, tx, ty, tz);
  }

  // L_=8 layers: final state lands in xA
  const int total = B_ * N_ * 16 + B_ * N_ * D_;
  write_out_kernel<<<(total + 255) / 256, 256, 0, stream>>>(frames, xA, (float*)d_out);
}

// Round 9
// 873.035 us; speedup vs baseline: 1.1230x; 1.1230x over previous
//
#include <hip/hip_runtime.h>
#include <hip/hip_bf16.h>
#include <math.h>

#define B_  2
#define N_  384
#define D_  256
#define PD_ 64
#define L_  8
#define H_  8
#define DH_ 32
#define GR  4      // rows per GEMM block
#define IT  8      // attention i-tile
#define RT_ 132    // relcT row stride (129 padded)

// ---------------- prologue: embed+LN, frames/t init, centered relpos, zero ff-target ------------
// grid = M, 256 threads
__global__ void prologue_kernel(const int* __restrict__ tokens, const float* __restrict__ tok_emb,
                                const float* __restrict__ lnw, const float* __restrict__ lnb,
                                const float* __restrict__ relpos,
                                float* __restrict__ x, float* __restrict__ frames,
                                float* __restrict__ tx, float* __restrict__ ty,
                                float* __restrict__ tz,
                                float* __restrict__ relc, float* __restrict__ relcT,
                                float* __restrict__ xz) {
  int row = blockIdx.x;            // b*N + n
  int n = row % N_;
  int d = threadIdx.x;             // 0..255
  __shared__ float rbuf[256];
  __shared__ float smr;
  if (d < 16) frames[row * 16 + d] = (d == 0 || d == 5 || d == 10 || d == 15) ? 1.0f : 0.0f;
  if (d == 16) tx[row] = 0.0f;
  if (d == 17) ty[row] = 0.0f;
  if (d == 18) tz[row] = 0.0f;
  xz[(size_t)row * D_ + d] = 0.0f;          // zero layer-0 ff accumulation target
  // rel row mean (blocks 0..128, wave 3)
  if (row < 129 && d >= 192) {
    int lane = d & 63;
    float s = relpos[row * PD_ + lane];
    #pragma unroll
    for (int off = 32; off >= 1; off >>= 1) s += __shfl_xor(s, off, 64);
    if (lane == 0) smr = s * (1.0f / PD_);
  }
  // embed + pos-enc + LN
  int tok = tokens[row];
  float val = tok_emb[tok * D_ + d];
  int i = d >> 1;
  float dv = expf((float)(2 * i) * (-logf(10000.0f) / (float)D_));
  float ang = (float)n * dv;
  val += (d & 1) ? cosf(ang) : sinf(ang);
  rbuf[d] = val; __syncthreads();          // smr visible after this
  for (int s = 128; s > 0; s >>= 1) { if (d < s) rbuf[d] += rbuf[d + s]; __syncthreads(); }
  float mean = rbuf[0] / D_;
  __syncthreads();
  rbuf[d] = val * val; __syncthreads();
  for (int s = 128; s > 0; s >>= 1) { if (d < s) rbuf[d] += rbuf[d + s]; __syncthreads(); }
  float var = rbuf[0] / D_ - mean * mean;
  float r = rsqrtf(var + 1e-5f);
  x[row * D_ + d] = (val - mean) * r * lnw[d] + lnb[d];
  // centered relpos + transpose
  if (row < 129 && d < PD_) {
    float cv = relpos[row * PD_ + d] - smr;
    relc[row * PD_ + d] = cv;
    relcT[d * RT_ + row] = cv;
  }
}

// ---------------- qkv unit (GR=4, k-chunk 4 x col-tile 64; K transposed) ----------------
__device__ __forceinline__ void qkv_unit(int bid, int tid, const float* __restrict__ x,
                                         const float* __restrict__ Wq, const float* __restrict__ Wk,
                                         const float* __restrict__ Wv,
                                         float* __restrict__ q, float* __restrict__ kt,
                                         float* __restrict__ v, float* sA) {
  int tile = bid & 3;
  int m = (bid >> 2) % 3;
  int r0 = (bid / 12) * GR;
  float* red = sA + GR * D_;       // 1024 floats
  {
    int r = tid >> 6, lane = tid & 63;
    ((float4*)(sA + r * D_))[lane] = ((const float4*)(x + (size_t)(r0 + r) * D_))[lane];
  }
  __syncthreads();
  const float* W = (m == 0) ? Wq : (m == 1) ? Wk : Wv;
  int kc = tid >> 6, c = tid & 63;
  const float* wp = W + (size_t)(kc * 64) * D_ + tile * 64 + c;
  const float* s0 = sA + kc * 64;
  float a0 = 0.f, a1 = 0.f, a2 = 0.f, a3 = 0.f;
  for (int kk = 0; kk < 64; kk += 4) {
    float w0 = wp[(size_t)kk * D_], w1 = wp[(size_t)(kk + 1) * D_];
    float w2 = wp[(size_t)(kk + 2) * D_], w3 = wp[(size_t)(kk + 3) * D_];
    float4 h0 = *(const float4*)(s0 + 0 * D_ + kk);
    float4 h1 = *(const float4*)(s0 + 1 * D_ + kk);
    float4 h2 = *(const float4*)(s0 + 2 * D_ + kk);
    float4 h3 = *(const float4*)(s0 + 3 * D_ + kk);
    a0 = fmaf(h0.x, w0, fmaf(h0.y, w1, fmaf(h0.z, w2, fmaf(h0.w, w3, a0))));
    a1 = fmaf(h1.x, w0, fmaf(h1.y, w1, fmaf(h1.z, w2, fmaf(h1.w, w3, a1))));
    a2 = fmaf(h2.x, w0, fmaf(h2.y, w1, fmaf(h2.z, w2, fmaf(h2.w, w3, a2))));
    a3 = fmaf(h3.x, w0, fmaf(h3.y, w1, fmaf(h3.z, w2, fmaf(h3.w, w3, a3))));
  }
  red[(kc * 4 + 0) * 64 + c] = a0;
  red[(kc * 4 + 1) * 64 + c] = a1;
  red[(kc * 4 + 2) * 64 + c] = a2;
  red[(kc * 4 + 3) * 64 + c] = a3;
  __syncthreads();
  int r = tid >> 6;
  float s = red[(0 * 4 + r) * 64 + c] + red[(1 * 4 + r) * 64 + c]
          + red[(2 * 4 + r) * 64 + c] + red[(3 * 4 + r) * 64 + c];
  int col = tile * 64 + c;
  int row = r0 + r;
  if (m == 1) {
    int b = row / N_, j = row % N_;
    int hh = col >> 5, dd = col & 31;
    kt[((size_t)(b * H_ + hh) * DH_ + dd) * N_ + j] = s;
  } else {
    float* O = (m == 0) ? q : v;
    O[(size_t)row * D_ + col] = s;
  }
}

// ---------------- proj unit: centered relu(x@Wop+bop) -> projc (+transposed); zero zbuf row ----
__device__ __forceinline__ void proj_unit(int row, int tid, const float* __restrict__ x,
                                          const float* __restrict__ Wop, const float* __restrict__ bop,
                                          float* __restrict__ projc, float* __restrict__ projcT,
                                          float* __restrict__ zbuf, float* smem) {
  float* sA  = smem;               // 256
  float* red = smem + 256;         // 256
  zbuf[(size_t)row * D_ + tid] = 0.0f;     // zero next ff accumulation target
  if (tid < 64) ((float4*)sA)[tid] = ((const float4*)(x + (size_t)row * D_))[tid];
  __syncthreads();
  int kc = tid >> 6, c = tid & 63;
  const float* wp = Wop + (kc * 64) * PD_ + c;
  const float* s0 = sA + kc * 64;
  float a0 = 0.f, a1 = 0.f, a2 = 0.f, a3 = 0.f;
  for (int kk = 0; kk < 64; kk += 4) {
    a0 = fmaf(s0[kk],     wp[(kk)     * PD_], a0);
    a1 = fmaf(s0[kk + 1], wp[(kk + 1) * PD_], a1);
    a2 = fmaf(s0[kk + 2], wp[(kk + 2) * PD_], a2);
    a3 = fmaf(s0[kk + 3], wp[(kk + 3) * PD_], a3);
  }
  red[kc * 64 + c] = (a0 + a1) + (a2 + a3);
  __syncthreads();
  if (tid < 64) {
    float acc = fmaxf(bop[tid] + red[tid] + red[64 + tid] + red[128 + tid] + red[192 + tid], 0.0f);
    float s = acc;
    #pragma unroll
    for (int off = 32; off >= 1; off >>= 1) s += __shfl_xor(s, off, 64);
    float cv = acc - s * (1.0f / PD_);
    projc[row * PD_ + tid] = cv;
    projcT[(size_t)tid * (B_ * N_) + row] = cv;
  }
}

// ---------------- standalone qkv (layer 0) ----------------
__global__ void qkv_kernel(const float* __restrict__ x, const float* __restrict__ Wq,
                           const float* __restrict__ Wk, const float* __restrict__ Wv,
                           float* __restrict__ q, float* __restrict__ kt, float* __restrict__ v) {
  __shared__ __align__(16) float smem[2048];
  qkv_unit(blockIdx.x, threadIdx.x, x, Wq, Wk, Wv, q, kt, v, smem);
}

// ---------------- combined proj(l) + qkv(l+1): both read only x ----------------
__global__ void proj_qkv_kernel(const float* __restrict__ x,
                                const float* __restrict__ Wop, const float* __restrict__ bop,
                                float* __restrict__ projc, float* __restrict__ projcT,
                                const float* __restrict__ Wq, const float* __restrict__ Wk,
                                const float* __restrict__ Wv,
                                float* __restrict__ q, float* __restrict__ kt,
                                float* __restrict__ v, float* __restrict__ zbuf) {
  __shared__ __align__(16) float smem[2048];
  int bid = blockIdx.x, tid = threadIdx.x;
  if (bid < B_ * N_) proj_unit(bid, tid, x, Wop, bop, projc, projcT, zbuf, smem);
  else               qkv_unit(bid - B_ * N_, tid, x, Wq, Wk, Wv, q, kt, v, smem);
}

// ---------------- fused FF: T += x + b2 + gelu(ffLN(x)@W1+b1)@W2, x = attnLN(S + bo) -----------
// grid = (M/GR)*8 = 1536, 256 threads. S holds x_resid + ao@Wo (attn-accumulated).
// Each block owns a 128-wide f-slice (split-K of W2); atomically accumulates into T (pre-zeroed).
__global__ void ff_fused_kernel(const float* __restrict__ S, const float* __restrict__ bo,
                                const float* __restrict__ alnw, const float* __restrict__ alnb,
                                const float* __restrict__ flnw, const float* __restrict__ flnb,
                                const float* __restrict__ W1, const float* __restrict__ b1,
                                const float* __restrict__ W2, const float* __restrict__ b2v,
                                float* __restrict__ T) {
  int bid = blockIdx.x;
  int tile = bid & 7;              // 128 f-cols each
  int r0 = (bid >> 3) * GR;
  int tid = threadIdx.x;
  __shared__ __align__(16) float sA[GR * D_];       // ff-LN'd h rows (4 KB)
  __shared__ __align__(16) float sX[GR * D_];       // attn-LN'd x rows (4 KB)
  __shared__ float red[2 * GR * 128];               // split-k partials (4 KB)
  __shared__ __align__(16) float sF[128 * 4];       // f tile [k][r] (2 KB)
  {
    int r = tid >> 6, lane = tid & 63;
    float4 v = ((const float4*)(S + (size_t)(r0 + r) * D_))[lane];
    float4 bo4 = ((const float4*)bo)[lane];
    v.x += bo4.x; v.y += bo4.y; v.z += bo4.z; v.w += bo4.w;
    // attn LN
    float s = v.x + v.y + v.z + v.w;
    float s2 = v.x * v.x + v.y * v.y + v.z * v.z + v.w * v.w;
    #pragma unroll
    for (int off = 32; off >= 1; off >>= 1) {
      s  += __shfl_xor(s, off, 64);
      s2 += __shfl_xor(s2, off, 64);
    }
    float mean = s * (1.0f / D_);
    float var = s2 * (1.0f / D_) - mean * mean;
    float rin = rsqrtf(var + 1e-5f);
    float4 aw = ((const float4*)alnw)[lane];
    float4 ab = ((const float4*)alnb)[lane];
    float4 x4;
    x4.x = (v.x - mean) * rin * aw.x + ab.x;
    x4.y = (v.y - mean) * rin * aw.y + ab.y;
    x4.z = (v.z - mean) * rin * aw.z + ab.z;
    x4.w = (v.w - mean) * rin * aw.w + ab.w;
    ((float4*)(sX + r * D_))[lane] = x4;
    // ff LN
    float t = x4.x + x4.y + x4.z + x4.w;
    float t2 = x4.x * x4.x + x4.y * x4.y + x4.z * x4.z + x4.w * x4.w;
    #pragma unroll
    for (int off = 32; off >= 1; off >>= 1) {
      t  += __shfl_xor(t, off, 64);
      t2 += __shfl_xor(t2, off, 64);
    }
    float mean2 = t * (1.0f / D_);
    float var2 = t2 * (1.0f / D_) - mean2 * mean2;
    float rin2 = rsqrtf(var2 + 1e-5f);
    float4 fw = ((const float4*)flnw)[lane];
    float4 fb = ((const float4*)flnb)[lane];
    float4 h4;
    h4.x = (x4.x - mean2) * rin2 * fw.x + fb.x;
    h4.y = (x4.y - mean2) * rin2 * fw.y + fb.y;
    h4.z = (x4.z - mean2) * rin2 * fw.z + fb.z;
    h4.w = (x4.w - mean2) * rin2 * fw.w + fb.w;
    ((float4*)(sA + r * D_))[lane] = h4;
  }
  __syncthreads();
  // ---- W1 GEMM: 2 k-chunks x 128 cols ----
  {
    int kc = tid >> 7, c = tid & 127;
    int col = tile * 128 + c;
    const float* wp = W1 + (size_t)(kc * 128) * 1024 + col;
    const float* s0 = sA + kc * 128;
    float a0 = 0.f, a1 = 0.f, a2 = 0.f, a3 = 0.f;
    for (int kk = 0; kk < 128; kk += 4) {
      float w0 = wp[(size_t)kk * 1024], w1 = wp[(size_t)(kk + 1) * 1024];
      float w2 = wp[(size_t)(kk + 2) * 1024], w3 = wp[(size_t)(kk + 3) * 1024];
      float4 h0 = *(const float4*)(s0 + 0 * D_ + kk);
      float4 h1 = *(const float4*)(s0 + 1 * D_ + kk);
      float4 h2 = *(const float4*)(s0 + 2 * D_ + kk);
      float4 h3 = *(const float4*)(s0 + 3 * D_ + kk);
      a0 = fmaf(h0.x, w0, fmaf(h0.y, w1, fmaf(h0.z, w2, fmaf(h0.w, w3, a0))));
      a1 = fmaf(h1.x, w0, fmaf(h1.y, w1, fmaf(h1.z, w2, fmaf(h1.w, w3, a1))));
      a2 = fmaf(h2.x, w0, fmaf(h2.y, w1, fmaf(h2.z, w2, fmaf(h2.w, w3, a2))));
      a3 = fmaf(h3.x, w0, fmaf(h3.y, w1, fmaf(h3.z, w2, fmaf(h3.w, w3, a3))));
    }
    red[(kc * 4 + 0) * 128 + c] = a0;
    red[(kc * 4 + 1) * 128 + c] = a1;
    red[(kc * 4 + 2) * 128 + c] = a2;
    red[(kc * 4 + 3) * 128 + c] = a3;
  }
  __syncthreads();
  // ---- gelu, f tile to LDS [k][r] ----
  {
    int rA = tid >> 7, c = tid & 127;
    int col = tile * 128 + c;
    #pragma unroll
    for (int p = 0; p < 2; p++) {
      int r = rA + p * 2;
      float s = red[(0 * 4 + r) * 128 + c] + red[(1 * 4 + r) * 128 + c] + b1[col];
      s = 0.5f * s * (1.0f + erff(s * 0.7071067811865475f));
      sF[c * 4 + r] = s;
    }
  }
  __syncthreads();
  // ---- W2 partial (128 k-slice x 256 out-cols), atomic accumulate ----
  {
    const float* w2p = W2 + (size_t)(tile * 128) * D_ + tid;
    float o0 = 0.f, o1 = 0.f, o2 = 0.f, o3 = 0.f;
    #pragma unroll 8
    for (int k = 0; k < 128; k++) {
      float w = w2p[(size_t)k * D_];
      float4 f4 = *(const float4*)(sF + k * 4);
      o0 = fmaf(f4.x, w, o0); o1 = fmaf(f4.y, w, o1);
      o2 = fmaf(f4.z, w, o2); o3 = fmaf(f4.w, w, o3);
    }
    if (tile == 0) {
      float bb2 = b2v[tid];
      o0 += sX[0 * D_ + tid] + bb2;
      o1 += sX[1 * D_ + tid] + bb2;
      o2 += sX[2 * D_ + tid] + bb2;
      o3 += sX[3 * D_ + tid] + bb2;
    }
    atomicAdd(&T[(size_t)(r0 + 0) * D_ + tid], o0);
    atomicAdd(&T[(size_t)(r0 + 1) * D_ + tid], o1);
    atomicAdd(&T[(size_t)(r0 + 2) * D_ + tid], o2);
    atomicAdd(&T[(size_t)(r0 + 3) * D_ + tid], o3);
  }
}

// ---------------- attention (staged, XCD-swizzled, PV row-pair reuse) + fused Wo partial --------
// grid = 768, 256 threads. Block remap: each XCD owns 2 heads x 48 tiles (K/V stay in its L2).
__global__ void attn_kernel(const float* __restrict__ Q, const float* __restrict__ KT,
                            const float* __restrict__ V,
                            const float* __restrict__ tx, const float* __restrict__ ty,
                            const float* __restrict__ tz,
                            const float* __restrict__ Wo, float* __restrict__ S) {
  // XCD-aware remap: wgid%8 = XCD (typical assignment); give each XCD 2 whole heads.
  int wgid = blockIdx.x;
  int xcd  = wgid & 7;
  int slot = wgid >> 3;            // 0..95
  int head = xcd * 2 + (slot / 48);// 0..15 == b*H + h
  int it   = slot % 48;
  int h = head & 7;
  int b = head >> 3;
  int i0 = it * IT;
  int tid = threadIdx.x;
  int wave = tid >> 6, lane = tid & 63;

  __shared__ __align__(16) float sQ[IT * DH_];
  __shared__ __align__(16) float sK[DH_ * 64];
  __shared__ __align__(16) float sV[64 * DH_];
  __shared__ __align__(16) float sS[IT][N_];
  __shared__ float sti[3][IT];
  __shared__ float sinv[IT];

  {
    int ii = tid >> 5, d = tid & 31;
    sQ[ii * DH_ + d] = Q[((size_t)(b * N_ + i0 + ii)) * D_ + h * DH_ + d];
  }
  if (tid < IT) {
    sti[0][tid] = tx[b * N_ + i0 + tid];
    sti[1][tid] = ty[b * N_ + i0 + tid];
    sti[2][tid] = tz[b * N_ + i0 + tid];
  }
  const float* ktb = KT + (size_t)(b * H_ + h) * DH_ * N_;
  const float* vb  = V + (size_t)b * N_ * D_ + h * DH_;
  const float* txb = tx + b * N_;
  const float* tyb = ty + b * N_;
  const float* tzb = tz + b * N_;
  __syncthreads();

  // hoist this wave's two Q rows into registers
  float4 q0r[8], q1r[8];
  #pragma unroll
  for (int t = 0; t < 8; t++) {
    q0r[t] = ((const float4*)(sQ + (wave * 2 + 0) * DH_))[t];
    q1r[t] = ((const float4*)(sQ + (wave * 2 + 1) * DH_))[t];
  }

  for (int jc = 0; jc < N_; jc += 64) {
    for (int idx = tid; idx < DH_ * 64; idx += 256) {
      int d = idx >> 6, jj = idx & 63;
      sK[d * 64 + jj] = ktb[(size_t)d * N_ + jc + jj];
    }
    __syncthreads();
    int jj = lane;
    float tjx = txb[jc + jj], tjy = tyb[jc + jj], tjz = tzb[jc + jj];
    float a0 = 0.f, a1 = 0.f;
    #pragma unroll
    for (int t = 0; t < 8; t++) {
      float k0 = sK[(4 * t + 0) * 64 + jj];
      float k1 = sK[(4 * t + 1) * 64 + jj];
      float k2 = sK[(4 * t + 2) * 64 + jj];
      float k3 = sK[(4 * t + 3) * 64 + jj];
      float4 qa = q0r[t], qb = q1r[t];
      a0 = fmaf(qa.x, k0, fmaf(qa.y, k1, fmaf(qa.z, k2, fmaf(qa.w, k3, a0))));
      a1 = fmaf(qb.x, k0, fmaf(qb.y, k1, fmaf(qb.z, k2, fmaf(qb.w, k3, a1))));
    }
    #pragma unroll
    for (int s = 0; s < 2; s++) {
      int ii = wave * 2 + s;
      float a = (s == 0) ? a0 : a1;
      float dx = sti[0][ii] - tjx;
      float dy = sti[1][ii] - tjy;
      float dz = sti[2][ii] - tjz;
      sS[ii][jc + jj] = a * 0.17677669529663689f - (dx * dx + dy * dy + dz * dz);
    }
    __syncthreads();
  }

  #pragma unroll
  for (int s = 0; s < 2; s++) {
    int ii = wave * 2 + s;
    float vrow[6];
    float m = -1e30f;
    #pragma unroll
    for (int t = 0; t < 6; t++) { vrow[t] = sS[ii][t * 64 + lane]; m = fmaxf(m, vrow[t]); }
    #pragma unroll
    for (int off = 32; off >= 1; off >>= 1) m = fmaxf(m, __shfl_xor(m, off, 64));
    float ps = 0.f;
    #pragma unroll
    for (int t = 0; t < 6; t++) {
      float e = expf(vrow[t] - m);
      sS[ii][t * 64 + lane] = e;
      ps += e;
    }
    #pragma unroll
    for (int off = 32; off >= 1; off >>= 1) ps += __shfl_xor(ps, off, 64);
    if (lane == 0) sinv[ii] = 1.0f / ps;
  }
  __syncthreads();

  // ---- PV with row-pair reuse: wave-uniform j-half, each thread owns rows (2p, 2p+1) ----
  // waves 0,1 -> j in [0,192); waves 2,3 -> j in [192,384). Each sV read feeds 2 fmas.
  int jh = wave >> 1;
  int p  = ((wave & 1) << 1) | (lane >> 5);   // row-pair 0..3
  int dd = lane & 31;
  int rA = 2 * p, rB = 2 * p + 1;
  float oA = 0.f, oB = 0.f;
  for (int jc = 0; jc < N_; jc += 64) {
    for (int idx = tid; idx < 64 * DH_; idx += 256) {
      int jj = idx >> 5, d = idx & 31;
      sV[jj * DH_ + d] = vb[(size_t)(jc + jj) * D_ + d];
    }
    __syncthreads();
    if ((jc / 192) == jh) {
      const float* sa = sS[rA] + jc;
      const float* sb = sS[rB] + jc;
      #pragma unroll
      for (int jj = 0; jj < 64; jj += 4) {
        float4 ea = *(const float4*)(sa + jj);
        float4 eb = *(const float4*)(sb + jj);
        float v0 = sV[(jj + 0) * DH_ + dd];
        float v1 = sV[(jj + 1) * DH_ + dd];
        float v2 = sV[(jj + 2) * DH_ + dd];
        float v3 = sV[(jj + 3) * DH_ + dd];
        oA = fmaf(ea.x, v0, fmaf(ea.y, v1, fmaf(ea.z, v2, fmaf(ea.w, v3, oA))));
        oB = fmaf(eb.x, v0, fmaf(eb.y, v1, fmaf(eb.z, v2, fmaf(eb.w, v3, oB))));
      }
    }
    __syncthreads();
  }
  // combine the two j-half partials (reuse sK as scratch; dead after QK)
  float* pr = sK;                  // pr[jh*256 + row*32 + dd]
  pr[jh * 256 + rA * 32 + dd] = oA;
  pr[jh * 256 + rB * 32 + dd] = oB;
  __syncthreads();
  {
    int ii = tid >> 5;
    sQ[tid] = (pr[tid] + pr[256 + tid]) * sinv[ii];   // sQ[ii*32+dd] = ao
  }
  __syncthreads();

  // ---- fused Wo partial: head-slice GEMM + atomics ----
  {
    const float* wo = Wo + (size_t)(h * DH_) * D_ + tid;   // col = tid
    float acc[8];
    #pragma unroll
    for (int r = 0; r < 8; r++) acc[r] = 0.f;
    for (int k = 0; k < DH_; k += 4) {
      float w0 = wo[(size_t)(k + 0) * D_];
      float w1 = wo[(size_t)(k + 1) * D_];
      float w2 = wo[(size_t)(k + 2) * D_];
      float w3 = wo[(size_t)(k + 3) * D_];
      #pragma unroll
      for (int r = 0; r < 8; r++) {
        float4 a4 = *(const float4*)(sQ + r * DH_ + k);
        acc[r] = fmaf(a4.x, w0, fmaf(a4.y, w1, fmaf(a4.z, w2, fmaf(a4.w, w3, acc[r]))));
      }
    }
    float* Sb = S + ((size_t)(b * N_ + i0)) * D_ + tid;
    #pragma unroll
    for (int r = 0; r < 8; r++) atomicAdd(Sb + (size_t)r * D_, acc[r]);
  }
}

// ---------------- fused pair LN-mean + head (shuffle-free pair phase) ----------------
// grid = M, 256 threads
__global__ void pair_head_kernel(const float* __restrict__ projc, const float* __restrict__ projcT,
                                 const float* __restrict__ relc, const float* __restrict__ relcT,
                                 const float* __restrict__ lnw, const float* __restrict__ lnb,
                                 const float* __restrict__ x,
                                 const float* __restrict__ Wf1, const float* __restrict__ bWf1,
                                 const float* __restrict__ Wf2, const float* __restrict__ bWf2,
                                 float* __restrict__ frames, float* __restrict__ tx,
                                 float* __restrict__ ty, float* __restrict__ tz) {
  const int M = B_ * N_;
  int row = blockIdx.x;            // b*N + i
  int b = row / N_;
  int i = row % N_;
  int tid = threadIdx.x;           // 256 = 4 waves
  int lane = tid & 63;
  int wave = tid >> 6;
  __shared__ float svpi[PD_];
  __shared__ float sr[N_];         // rinv per j
  __shared__ float red[4][PD_];
  __shared__ float sfeat[320];
  __shared__ float fred[2][128];
  __shared__ float sg[128];
  __shared__ float sraw[9];

  if (tid < PD_) svpi[tid] = projc[row * PD_ + tid];
  if (tid < D_) sfeat[tid] = x[(size_t)row * D_ + tid];
  __syncthreads();

  // ---- pass A: rinv[j] via thread-per-j (coalesced transposed reads, no shuffles) ----
  {
    int jA = tid;                  // 0..255
    int raA = jA - i; raA = raA < -64 ? -64 : (raA > 64 ? 64 : raA); raA += 64;
    const float* pA = projcT + b * N_ + jA;
    const float* rA = relcT + raA;
    float s2A = 0.f;
    #pragma unroll 8
    for (int c = 0; c < PD_; c++) {
      float dA = svpi[c] + pA[(size_t)c * M] + rA[c * RT_];
      s2A = fmaf(dA, dA, s2A);
    }
    sr[jA] = rsqrtf(s2A * (1.0f / PD_) + 1e-5f);
    if (tid < 128) {
      int jB = tid + 256;          // 256..383
      int raB = jB - i; raB = raB < -64 ? -64 : (raB > 64 ? 64 : raB); raB += 64;
      const float* pB = projcT + b * N_ + jB;
      const float* rB = relcT + raB;
      float s2B = 0.f;
      #pragma unroll 8
      for (int c = 0; c < PD_; c++) {
        float dB = svpi[c] + pB[(size_t)c * M] + rB[c * RT_];
        s2B = fmaf(dB, dB, s2B);
      }
      sr[jB] = rsqrtf(s2B * (1.0f / PD_) + 1e-5f);
    }
  }
  __syncthreads();

  // ---- pass B: per-channel accumulation (row-major coalesced, no shuffles) ----
  {
    float vpl = svpi[lane];
    const float* pb = projc + (size_t)b * N_ * PD_;
    float acc = 0.0f;
    for (int j = wave * 2; j < N_; j += 8) {
      int ja = j, jb = j + 1;
      int ra = ja - i; ra = ra < -64 ? -64 : (ra > 64 ? 64 : ra); ra += 64;
      int rb = jb - i; rb = rb < -64 ? -64 : (rb > 64 ? 64 : rb); rb += 64;
      float da = vpl + pb[ja * PD_ + lane] + relc[ra * PD_ + lane];
      float db = vpl + pb[jb * PD_ + lane] + relc[rb * PD_ + lane];
      acc = fmaf(da, sr[ja], fmaf(db, sr[jb], acc));
    }
    red[wave][lane] = acc;
  }
  __syncthreads();
  if (wave == 0) {
    float s = red[0][lane] + red[1][lane] + red[2][lane] + red[3][lane];
    sfeat[D_ + lane] = lnb[lane] + s * lnw[lane] * (1.0f / N_);
  }
  __syncthreads();

  // ---- fc1 silu (320 -> 128), 2 k-chunks x 128 cols ----
  int kc = tid >> 7, c = tid & 127;
  int koff = kc * 160;
  const float* wp = Wf1 + (size_t)koff * 128 + c;
  const float* s0 = sfeat + koff;
  float a0 = 0.f, a1 = 0.f, a2 = 0.f, a3 = 0.f;
  for (int kk = 0; kk < 160; kk += 4) {
    a0 = fmaf(s0[kk],     wp[(size_t)kk * 128],       a0);
    a1 = fmaf(s0[kk + 1], wp[(size_t)(kk + 1) * 128], a1);
    a2 = fmaf(s0[kk + 2], wp[(size_t)(kk + 2) * 128], a2);
    a3 = fmaf(s0[kk + 3], wp[(size_t)(kk + 3) * 128], a3);
  }
  fred[kc][c] = (a0 + a1) + (a2 + a3);
  __syncthreads();
  if (tid < 128) {
    float g = fred[0][tid] + fred[1][tid] + bWf1[tid];
    sg[tid] = g / (1.0f + expf(-g));
  }
  __syncthreads();

  // ---- fc2 (128 -> 9), rot6d, frame write ----
  if (tid < 9) {
    float b0 = 0.f, b1v = 0.f;
    for (int kk = 0; kk < 128; kk += 2) {
      b0  = fmaf(sg[kk],     Wf2[(kk)     * 9 + tid], b0);
      b1v = fmaf(sg[kk + 1], Wf2[(kk + 1) * 9 + tid], b1v);
    }
    sraw[tid] = bWf2[tid] + b0 + b1v;
  }
  __syncthreads();
  if (tid == 0) {
    float a1x = sraw[0], a1y = sraw[1], a1z = sraw[2];
    float a2x = sraw[3], a2y = sraw[4], a2z = sraw[5];
    float n1 = sqrtf(a1x * a1x + a1y * a1y + a1z * a1z + 1e-8f);
    float b1x = a1x / n1, b1y = a1y / n1, b1z = a1z / n1;
    float dp = b1x * a2x + b1y * a2y + b1z * a2z;
    float px = a2x - dp * b1x, py = a2y - dp * b1y, pz = a2z - dp * b1z;
    float n2 = sqrtf(px * px + py * py + pz * pz + 1e-8f);
    float b2x = px / n2, b2y = py / n2, b2z = pz / n2;
    float b3x = b1y * b2z - b1z * b2y;
    float b3y = b1z * b2x - b1x * b2z;
    float b3z = b1x * b2y - b1y * b2x;
    float* f = frames + row * 16;
    f[0]  = b1x; f[1]  = b1y; f[2]  = b1z; f[3]  = sraw[6];
    f[4]  = b2x; f[5]  = b2y; f[6]  = b2z; f[7]  = sraw[7];
    f[8]  = b3x; f[9]  = b3y; f[10] = b3z; f[11] = sraw[8];
    f[12] = 0.0f; f[13] = 0.0f; f[14] = 0.0f; f[15] = 1.0f;
    tx[row] = sraw[6];
    ty[row] = sraw[7];
    tz[row] = sraw[8];
  }
}

// ---------------- output ----------------
__global__ void write_out_kernel(const float* __restrict__ frames, const float* __restrict__ x,
                                 float* __restrict__ out) {
  int i = blockIdx.x * 256 + threadIdx.x;
  const int nf = B_ * N_ * 16;
  const int total = nf + B_ * N_ * D_;
  if (i < nf) out[i] = frames[i];
  else if (i < total) out[i] = x[i - nf];
}

extern "C" void kernel_launch(void* const* d_in, const int* in_sizes, int n_in,
                              void* d_out, int out_size, void* d_ws, size_t ws_size,
                              hipStream_t stream) {
  const int*   tokens    = (const int*)  d_in[0];
  const float* tok_emb   = (const float*)d_in[1];
  const float* emb_ln_w  = (const float*)d_in[2];
  const float* emb_ln_b  = (const float*)d_in[3];
  const float* Wq        = (const float*)d_in[4];
  const float* Wk        = (const float*)d_in[5];
  const float* Wv        = (const float*)d_in[6];
  const float* Wo        = (const float*)d_in[7];
  const float* bo        = (const float*)d_in[8];
  const float* attn_ln_w = (const float*)d_in[9];
  const float* attn_ln_b = (const float*)d_in[10];
  const float* ff_ln_w   = (const float*)d_in[11];
  const float* ff_ln_b   = (const float*)d_in[12];
  const float* W1        = (const float*)d_in[13];
  const float* b1        = (const float*)d_in[14];
  const float* W2        = (const float*)d_in[15];
  const float* b2        = (const float*)d_in[16];
  const float* Wop       = (const float*)d_in[17];
  const float* bop       = (const float*)d_in[18];
  const float* relpos    = (const float*)d_in[19];
  const float* pair_ln_w = (const float*)d_in[20];
  const float* pair_ln_b = (const float*)d_in[21];
  const float* Wf1       = (const float*)d_in[22];
  const float* bWf1      = (const float*)d_in[23];
  const float* Wf2       = (const float*)d_in[24];
  const float* bWf2      = (const float*)d_in[25];

  const int M = B_ * N_;           // 768
  const int XE = M * D_;           // 196608
  float* ws     = (float*)d_ws;
  float* frames = ws;                      // 12288
  float* projc  = frames + M * 16;         // 49152
  float* projcT = projc  + M * PD_;        // 49152
  float* relc   = projcT + M * PD_;        // 8256 (pad 8320)
  float* relcT  = relc   + 8320;           // 64*132 = 8448
  float* tx     = relcT  + 8448;           // 768
  float* ty     = tx     + M;              // 768
  float* tz     = ty     + M;              // 768
  float* xA     = tz     + M;              // XE  (state ping)
  float* xB     = xA + XE;                 // XE  (state pong)
  float* q      = xB + XE;                 // XE
  float* kt     = q  + XE;                 // XE (K transposed [b,h,d,j])
  float* v      = kt + XE;                 // XE

  prologue_kernel<<<M, 256, 0, stream>>>(tokens, tok_emb, emb_ln_w, emb_ln_b, relpos,
                                         xA, frames, tx, ty, tz, relc, relcT, xB);
  qkv_kernel<<<(M / GR) * 12, 256, 0, stream>>>(xA, Wq, Wk, Wv, q, kt, v);

  for (int l = 0; l < L_; l++) {
    float* Sin  = (l & 1) ? xB : xA;       // holds x_l; attn accumulates ao@Wo into it
    float* Sout = (l & 1) ? xA : xB;       // pre-zeroed; ff accumulates new state
    attn_kernel<<<B_ * H_ * (N_ / IT), 256, 0, stream>>>(
        q, kt, v, tx, ty, tz, Wo + (size_t)l * D_ * D_, Sin);
    ff_fused_kernel<<<(M / GR) * 8, 256, 0, stream>>>(
        Sin, bo + l * D_,
        attn_ln_w + l * D_, attn_ln_b + l * D_,
        ff_ln_w + l * D_, ff_ln_b + l * D_,
        W1 + (size_t)l * D_ * 1024, b1 + l * 1024,
        W2 + (size_t)l * 1024 * D_, b2 + l * D_, Sout);
    if (l < L_ - 1) {
      int lq = l + 1;
      proj_qkv_kernel<<<M + (M / GR) * 12, 256, 0, stream>>>(
          Sout, Wop, bop, projc, projcT,
          Wq + (size_t)lq * D_ * D_, Wk + (size_t)lq * D_ * D_, Wv + (size_t)lq * D_ * D_,
          q, kt, v, Sin);
    } else {
      proj_qkv_kernel<<<M, 256, 0, stream>>>(Sout, Wop, bop, projc, projcT,
                                             Wq, Wk, Wv, q, kt, v, Sin);
    }
    pair_head_kernel<<<M, 256, 0, stream>>>(projc, projcT, relc, relcT, pair_ln_w, pair_ln_b,
                                            Sout, Wf1, bWf1, Wf2, bWf2, frames, tx, ty, tz);
  }

  // L_=8 layers: final state lands in xA
  const int total = B_ * N_ * 16 + B_ * N_ * D_;
  write_out_kernel<<<(total + 255) / 256, 256, 0, stream>>>(frames, xA, (float*)d_out);
}

// Round 10
// 865.022 us; speedup vs baseline: 1.1334x; 1.0093x over previous
//
#include <hip/hip_runtime.h>
#include <hip/hip_bf16.h>
#include <math.h>

#define B_  2
#define N_  384
#define D_  256
#define PD_ 64
#define L_  8
#define H_  8
#define DH_ 32
#define GR  4      // rows per GEMM block
#define IT  8      // attention i-tile
#define RT_ 132    // relcT row stride (129 padded)

// ---------------- prologue: embed+LN, frames/t init, centered relpos, zero ff-target ------------
// grid = M, 256 threads
__global__ void prologue_kernel(const int* __restrict__ tokens, const float* __restrict__ tok_emb,
                                const float* __restrict__ lnw, const float* __restrict__ lnb,
                                const float* __restrict__ relpos,
                                float* __restrict__ x, float* __restrict__ frames,
                                float* __restrict__ tx, float* __restrict__ ty,
                                float* __restrict__ tz,
                                float* __restrict__ relc, float* __restrict__ relcT,
                                float* __restrict__ xz) {
  int row = blockIdx.x;            // b*N + n
  int n = row % N_;
  int d = threadIdx.x;             // 0..255
  __shared__ float rbuf[256];
  __shared__ float smr;
  if (d < 16) frames[row * 16 + d] = (d == 0 || d == 5 || d == 10 || d == 15) ? 1.0f : 0.0f;
  if (d == 16) tx[row] = 0.0f;
  if (d == 17) ty[row] = 0.0f;
  if (d == 18) tz[row] = 0.0f;
  xz[(size_t)row * D_ + d] = 0.0f;          // zero layer-0 ff accumulation target
  // rel row mean (blocks 0..128, wave 3)
  if (row < 129 && d >= 192) {
    int lane = d & 63;
    float s = relpos[row * PD_ + lane];
    #pragma unroll
    for (int off = 32; off >= 1; off >>= 1) s += __shfl_xor(s, off, 64);
    if (lane == 0) smr = s * (1.0f / PD_);
  }
  // embed + pos-enc + LN
  int tok = tokens[row];
  float val = tok_emb[tok * D_ + d];
  int i = d >> 1;
  float dv = expf((float)(2 * i) * (-logf(10000.0f) / (float)D_));
  float ang = (float)n * dv;
  val += (d & 1) ? cosf(ang) : sinf(ang);
  rbuf[d] = val; __syncthreads();          // smr visible after this
  for (int s = 128; s > 0; s >>= 1) { if (d < s) rbuf[d] += rbuf[d + s]; __syncthreads(); }
  float mean = rbuf[0] / D_;
  __syncthreads();
  rbuf[d] = val * val; __syncthreads();
  for (int s = 128; s > 0; s >>= 1) { if (d < s) rbuf[d] += rbuf[d + s]; __syncthreads(); }
  float var = rbuf[0] / D_ - mean * mean;
  float r = rsqrtf(var + 1e-5f);
  x[row * D_ + d] = (val - mean) * r * lnw[d] + lnb[d];
  // centered relpos + transpose
  if (row < 129 && d < PD_) {
    float cv = relpos[row * PD_ + d] - smr;
    relc[row * PD_ + d] = cv;
    relcT[d * RT_ + row] = cv;
  }
}

// ---------------- qkv unit (GR=4, 8 k-chunks x 32 col-threads, 2 cols/thread; K transposed) ----
// Same grid/threads/fma/global-loads as before; LDS b128 issues halved (64 -> 32 per thread).
__device__ __forceinline__ void qkv_unit(int bid, int tid, const float* __restrict__ x,
                                         const float* __restrict__ Wq, const float* __restrict__ Wk,
                                         const float* __restrict__ Wv,
                                         float* __restrict__ q, float* __restrict__ kt,
                                         float* __restrict__ v, float* sA) {
  int tile = bid & 3;
  int m = (bid >> 2) % 3;
  int r0 = (bid / 12) * GR;
  float* red = sA + GR * D_;       // 2048 floats (8 kc x 4 rows x 64 cols)
  {
    int r = tid >> 6, lane = tid & 63;
    ((float4*)(sA + r * D_))[lane] = ((const float4*)(x + (size_t)(r0 + r) * D_))[lane];
  }
  __syncthreads();
  const float* W = (m == 0) ? Wq : (m == 1) ? Wk : Wv;
  int kc = tid >> 5, c = tid & 31;     // 8 k-chunks (32-k each) x 32 col-threads (cols c, c+32)
  const float* wp = W + (size_t)(kc * 32) * D_ + tile * 64 + c;
  const float* s0 = sA + kc * 32;
  float a0 = 0.f, a1 = 0.f, a2 = 0.f, a3 = 0.f;   // col c
  float b0 = 0.f, b1 = 0.f, b2 = 0.f, b3 = 0.f;   // col c+32
  for (int kk = 0; kk < 32; kk += 4) {
    float w0 = wp[(size_t)kk * D_],       w1 = wp[(size_t)(kk + 1) * D_];
    float w2 = wp[(size_t)(kk + 2) * D_], w3 = wp[(size_t)(kk + 3) * D_];
    float u0 = wp[(size_t)kk * D_ + 32],       u1 = wp[(size_t)(kk + 1) * D_ + 32];
    float u2 = wp[(size_t)(kk + 2) * D_ + 32], u3 = wp[(size_t)(kk + 3) * D_ + 32];
    float4 h0 = *(const float4*)(s0 + 0 * D_ + kk);
    float4 h1 = *(const float4*)(s0 + 1 * D_ + kk);
    float4 h2 = *(const float4*)(s0 + 2 * D_ + kk);
    float4 h3 = *(const float4*)(s0 + 3 * D_ + kk);
    a0 = fmaf(h0.x, w0, fmaf(h0.y, w1, fmaf(h0.z, w2, fmaf(h0.w, w3, a0))));
    a1 = fmaf(h1.x, w0, fmaf(h1.y, w1, fmaf(h1.z, w2, fmaf(h1.w, w3, a1))));
    a2 = fmaf(h2.x, w0, fmaf(h2.y, w1, fmaf(h2.z, w2, fmaf(h2.w, w3, a2))));
    a3 = fmaf(h3.x, w0, fmaf(h3.y, w1, fmaf(h3.z, w2, fmaf(h3.w, w3, a3))));
    b0 = fmaf(h0.x, u0, fmaf(h0.y, u1, fmaf(h0.z, u2, fmaf(h0.w, u3, b0))));
    b1 = fmaf(h1.x, u0, fmaf(h1.y, u1, fmaf(h1.z, u2, fmaf(h1.w, u3, b1))));
    b2 = fmaf(h2.x, u0, fmaf(h2.y, u1, fmaf(h2.z, u2, fmaf(h2.w, u3, b2))));
    b3 = fmaf(h3.x, u0, fmaf(h3.y, u1, fmaf(h3.z, u2, fmaf(h3.w, u3, b3))));
  }
  red[(kc * 4 + 0) * 64 + c] = a0;
  red[(kc * 4 + 1) * 64 + c] = a1;
  red[(kc * 4 + 2) * 64 + c] = a2;
  red[(kc * 4 + 3) * 64 + c] = a3;
  red[(kc * 4 + 0) * 64 + 32 + c] = b0;
  red[(kc * 4 + 1) * 64 + 32 + c] = b1;
  red[(kc * 4 + 2) * 64 + 32 + c] = b2;
  red[(kc * 4 + 3) * 64 + 32 + c] = b3;
  __syncthreads();
  int r = tid >> 6, c64 = tid & 63;
  float s = 0.f;
  #pragma unroll
  for (int k8 = 0; k8 < 8; k8++) s += red[(k8 * 4 + r) * 64 + c64];
  int col = tile * 64 + c64;
  int row = r0 + r;
  if (m == 1) {
    int b = row / N_, j = row % N_;
    int hh = col >> 5, dd = col & 31;
    kt[((size_t)(b * H_ + hh) * DH_ + dd) * N_ + j] = s;
  } else {
    float* O = (m == 0) ? q : v;
    O[(size_t)row * D_ + col] = s;
  }
}

// ---------------- proj unit: centered relu(x@Wop+bop) -> projc (+transposed); zero zbuf row ----
__device__ __forceinline__ void proj_unit(int row, int tid, const float* __restrict__ x,
                                          const float* __restrict__ Wop, const float* __restrict__ bop,
                                          float* __restrict__ projc, float* __restrict__ projcT,
                                          float* __restrict__ zbuf, float* smem) {
  float* sA  = smem;               // 256
  float* red = smem + 256;         // 256
  zbuf[(size_t)row * D_ + tid] = 0.0f;     // zero next ff accumulation target
  if (tid < 64) ((float4*)sA)[tid] = ((const float4*)(x + (size_t)row * D_))[tid];
  __syncthreads();
  int kc = tid >> 6, c = tid & 63;
  const float* wp = Wop + (kc * 64) * PD_ + c;
  const float* s0 = sA + kc * 64;
  float a0 = 0.f, a1 = 0.f, a2 = 0.f, a3 = 0.f;
  for (int kk = 0; kk < 64; kk += 4) {
    a0 = fmaf(s0[kk],     wp[(kk)     * PD_], a0);
    a1 = fmaf(s0[kk + 1], wp[(kk + 1) * PD_], a1);
    a2 = fmaf(s0[kk + 2], wp[(kk + 2) * PD_], a2);
    a3 = fmaf(s0[kk + 3], wp[(kk + 3) * PD_], a3);
  }
  red[kc * 64 + c] = (a0 + a1) + (a2 + a3);
  __syncthreads();
  if (tid < 64) {
    float acc = fmaxf(bop[tid] + red[tid] + red[64 + tid] + red[128 + tid] + red[192 + tid], 0.0f);
    float s = acc;
    #pragma unroll
    for (int off = 32; off >= 1; off >>= 1) s += __shfl_xor(s, off, 64);
    float cv = acc - s * (1.0f / PD_);
    projc[row * PD_ + tid] = cv;
    projcT[(size_t)tid * (B_ * N_) + row] = cv;
  }
}

// ---------------- standalone qkv (layer 0) ----------------
__global__ void qkv_kernel(const float* __restrict__ x, const float* __restrict__ Wq,
                           const float* __restrict__ Wk, const float* __restrict__ Wv,
                           float* __restrict__ q, float* __restrict__ kt, float* __restrict__ v) {
  __shared__ __align__(16) float smem[GR * D_ + 2048];
  qkv_unit(blockIdx.x, threadIdx.x, x, Wq, Wk, Wv, q, kt, v, smem);
}

// ---------------- combined proj(l) + qkv(l+1): both read only x ----------------
__global__ void proj_qkv_kernel(const float* __restrict__ x,
                                const float* __restrict__ Wop, const float* __restrict__ bop,
                                float* __restrict__ projc, float* __restrict__ projcT,
                                const float* __restrict__ Wq, const float* __restrict__ Wk,
                                const float* __restrict__ Wv,
                                float* __restrict__ q, float* __restrict__ kt,
                                float* __restrict__ v, float* __restrict__ zbuf) {
  __shared__ __align__(16) float smem[GR * D_ + 2048];
  int bid = blockIdx.x, tid = threadIdx.x;
  if (bid < B_ * N_) proj_unit(bid, tid, x, Wop, bop, projc, projcT, zbuf, smem);
  else               qkv_unit(bid - B_ * N_, tid, x, Wq, Wk, Wv, q, kt, v, smem);
}

// ---------------- fused FF: T += x + b2 + gelu(ffLN(x)@W1+b1)@W2, x = attnLN(S + bo) -----------
// grid = (M/GR)*8 = 1536, 256 threads. W1 phase: 4 k-chunks x 64 col-threads, 2 cols/thread
// (same grid/fma/global-loads; LDS b128 issues halved 128 -> 64 per thread).
__global__ void ff_fused_kernel(const float* __restrict__ S, const float* __restrict__ bo,
                                const float* __restrict__ alnw, const float* __restrict__ alnb,
                                const float* __restrict__ flnw, const float* __restrict__ flnb,
                                const float* __restrict__ W1, const float* __restrict__ b1,
                                const float* __restrict__ W2, const float* __restrict__ b2v,
                                float* __restrict__ T) {
  int bid = blockIdx.x;
  int tile = bid & 7;              // 128 f-cols each
  int r0 = (bid >> 3) * GR;
  int tid = threadIdx.x;
  __shared__ __align__(16) float sA[GR * D_];       // ff-LN'd h rows (4 KB)
  __shared__ __align__(16) float sX[GR * D_];       // attn-LN'd x rows (4 KB)
  __shared__ float red[4 * GR * 128];               // split-k partials (8 KB)
  __shared__ __align__(16) float sF[128 * 4];       // f tile [k][r] (2 KB)
  {
    int r = tid >> 6, lane = tid & 63;
    float4 v = ((const float4*)(S + (size_t)(r0 + r) * D_))[lane];
    float4 bo4 = ((const float4*)bo)[lane];
    v.x += bo4.x; v.y += bo4.y; v.z += bo4.z; v.w += bo4.w;
    // attn LN
    float s = v.x + v.y + v.z + v.w;
    float s2 = v.x * v.x + v.y * v.y + v.z * v.z + v.w * v.w;
    #pragma unroll
    for (int off = 32; off >= 1; off >>= 1) {
      s  += __shfl_xor(s, off, 64);
      s2 += __shfl_xor(s2, off, 64);
    }
    float mean = s * (1.0f / D_);
    float var = s2 * (1.0f / D_) - mean * mean;
    float rin = rsqrtf(var + 1e-5f);
    float4 aw = ((const float4*)alnw)[lane];
    float4 ab = ((const float4*)alnb)[lane];
    float4 x4;
    x4.x = (v.x - mean) * rin * aw.x + ab.x;
    x4.y = (v.y - mean) * rin * aw.y + ab.y;
    x4.z = (v.z - mean) * rin * aw.z + ab.z;
    x4.w = (v.w - mean) * rin * aw.w + ab.w;
    ((float4*)(sX + r * D_))[lane] = x4;
    // ff LN
    float t = x4.x + x4.y + x4.z + x4.w;
    float t2 = x4.x * x4.x + x4.y * x4.y + x4.z * x4.z + x4.w * x4.w;
    #pragma unroll
    for (int off = 32; off >= 1; off >>= 1) {
      t  += __shfl_xor(t, off, 64);
      t2 += __shfl_xor(t2, off, 64);
    }
    float mean2 = t * (1.0f / D_);
    float var2 = t2 * (1.0f / D_) - mean2 * mean2;
    float rin2 = rsqrtf(var2 + 1e-5f);
    float4 fw = ((const float4*)flnw)[lane];
    float4 fb = ((const float4*)flnb)[lane];
    float4 h4;
    h4.x = (x4.x - mean2) * rin2 * fw.x + fb.x;
    h4.y = (x4.y - mean2) * rin2 * fw.y + fb.y;
    h4.z = (x4.z - mean2) * rin2 * fw.z + fb.z;
    h4.w = (x4.w - mean2) * rin2 * fw.w + fb.w;
    ((float4*)(sA + r * D_))[lane] = h4;
  }
  __syncthreads();
  // ---- W1 GEMM: 4 k-chunks (64-k) x 64 col-threads, cols c and c+64 ----
  {
    int kc = tid >> 6, c = tid & 63;
    int col = tile * 128 + c;
    const float* wp = W1 + (size_t)(kc * 64) * 1024 + col;
    const float* s0 = sA + kc * 64;
    float a0 = 0.f, a1 = 0.f, a2 = 0.f, a3 = 0.f;   // col c
    float b0 = 0.f, b1v = 0.f, b2 = 0.f, b3 = 0.f;  // col c+64
    for (int kk = 0; kk < 64; kk += 4) {
      float w0 = wp[(size_t)kk * 1024],       w1 = wp[(size_t)(kk + 1) * 1024];
      float w2 = wp[(size_t)(kk + 2) * 1024], w3 = wp[(size_t)(kk + 3) * 1024];
      float u0 = wp[(size_t)kk * 1024 + 64],       u1 = wp[(size_t)(kk + 1) * 1024 + 64];
      float u2 = wp[(size_t)(kk + 2) * 1024 + 64], u3 = wp[(size_t)(kk + 3) * 1024 + 64];
      float4 h0 = *(const float4*)(s0 + 0 * D_ + kk);
      float4 h1 = *(const float4*)(s0 + 1 * D_ + kk);
      float4 h2 = *(const float4*)(s0 + 2 * D_ + kk);
      float4 h3 = *(const float4*)(s0 + 3 * D_ + kk);
      a0  = fmaf(h0.x, w0, fmaf(h0.y, w1, fmaf(h0.z, w2, fmaf(h0.w, w3, a0))));
      a1  = fmaf(h1.x, w0, fmaf(h1.y, w1, fmaf(h1.z, w2, fmaf(h1.w, w3, a1))));
      a2  = fmaf(h2.x, w0, fmaf(h2.y, w1, fmaf(h2.z, w2, fmaf(h2.w, w3, a2))));
      a3  = fmaf(h3.x, w0, fmaf(h3.y, w1, fmaf(h3.z, w2, fmaf(h3.w, w3, a3))));
      b0  = fmaf(h0.x, u0, fmaf(h0.y, u1, fmaf(h0.z, u2, fmaf(h0.w, u3, b0))));
      b1v = fmaf(h1.x, u0, fmaf(h1.y, u1, fmaf(h1.z, u2, fmaf(h1.w, u3, b1v))));
      b2  = fmaf(h2.x, u0, fmaf(h2.y, u1, fmaf(h2.z, u2, fmaf(h2.w, u3, b2))));
      b3  = fmaf(h3.x, u0, fmaf(h3.y, u1, fmaf(h3.z, u2, fmaf(h3.w, u3, b3))));
    }
    red[(kc * 4 + 0) * 128 + c] = a0;
    red[(kc * 4 + 1) * 128 + c] = a1;
    red[(kc * 4 + 2) * 128 + c] = a2;
    red[(kc * 4 + 3) * 128 + c] = a3;
    red[(kc * 4 + 0) * 128 + 64 + c] = b0;
    red[(kc * 4 + 1) * 128 + 64 + c] = b1v;
    red[(kc * 4 + 2) * 128 + 64 + c] = b2;
    red[(kc * 4 + 3) * 128 + 64 + c] = b3;
  }
  __syncthreads();
  // ---- gelu, f tile to LDS [k][r] (sum 4 split-k partials) ----
  {
    int rA = tid >> 7, c = tid & 127;
    int col = tile * 128 + c;
    #pragma unroll
    for (int p = 0; p < 2; p++) {
      int r = rA + p * 2;
      float s = red[(0 * 4 + r) * 128 + c] + red[(1 * 4 + r) * 128 + c]
              + red[(2 * 4 + r) * 128 + c] + red[(3 * 4 + r) * 128 + c] + b1[col];
      s = 0.5f * s * (1.0f + erff(s * 0.7071067811865475f));
      sF[c * 4 + r] = s;
    }
  }
  __syncthreads();
  // ---- W2 partial (128 k-slice x 256 out-cols), atomic accumulate ----
  {
    const float* w2p = W2 + (size_t)(tile * 128) * D_ + tid;
    float o0 = 0.f, o1 = 0.f, o2 = 0.f, o3 = 0.f;
    #pragma unroll 8
    for (int k = 0; k < 128; k++) {
      float w = w2p[(size_t)k * D_];
      float4 f4 = *(const float4*)(sF + k * 4);
      o0 = fmaf(f4.x, w, o0); o1 = fmaf(f4.y, w, o1);
      o2 = fmaf(f4.z, w, o2); o3 = fmaf(f4.w, w, o3);
    }
    if (tile == 0) {
      float bb2 = b2v[tid];
      o0 += sX[0 * D_ + tid] + bb2;
      o1 += sX[1 * D_ + tid] + bb2;
      o2 += sX[2 * D_ + tid] + bb2;
      o3 += sX[3 * D_ + tid] + bb2;
    }
    atomicAdd(&T[(size_t)(r0 + 0) * D_ + tid], o0);
    atomicAdd(&T[(size_t)(r0 + 1) * D_ + tid], o1);
    atomicAdd(&T[(size_t)(r0 + 2) * D_ + tid], o2);
    atomicAdd(&T[(size_t)(r0 + 3) * D_ + tid], o3);
  }
}

// ---------------- attention (staged, XCD-swizzled, PV row-pair reuse) + fused Wo partial --------
// grid = 768, 256 threads. Block remap: each XCD owns 2 heads x 48 tiles (K/V stay in its L2).
__global__ void attn_kernel(const float* __restrict__ Q, const float* __restrict__ KT,
                            const float* __restrict__ V,
                            const float* __restrict__ tx, const float* __restrict__ ty,
                            const float* __restrict__ tz,
                            const float* __restrict__ Wo, float* __restrict__ S) {
  // XCD-aware remap: wgid%8 = XCD (typical assignment); give each XCD 2 whole heads.
  int wgid = blockIdx.x;
  int xcd  = wgid & 7;
  int slot = wgid >> 3;            // 0..95
  int head = xcd * 2 + (slot / 48);// 0..15 == b*H + h
  int it   = slot % 48;
  int h = head & 7;
  int b = head >> 3;
  int i0 = it * IT;
  int tid = threadIdx.x;
  int wave = tid >> 6, lane = tid & 63;

  __shared__ __align__(16) float sQ[IT * DH_];
  __shared__ __align__(16) float sK[DH_ * 64];
  __shared__ __align__(16) float sV[64 * DH_];
  __shared__ __align__(16) float sS[IT][N_];
  __shared__ float sti[3][IT];
  __shared__ float sinv[IT];

  {
    int ii = tid >> 5, d = tid & 31;
    sQ[ii * DH_ + d] = Q[((size_t)(b * N_ + i0 + ii)) * D_ + h * DH_ + d];
  }
  if (tid < IT) {
    sti[0][tid] = tx[b * N_ + i0 + tid];
    sti[1][tid] = ty[b * N_ + i0 + tid];
    sti[2][tid] = tz[b * N_ + i0 + tid];
  }
  const float* ktb = KT + (size_t)(b * H_ + h) * DH_ * N_;
  const float* vb  = V + (size_t)b * N_ * D_ + h * DH_;
  const float* txb = tx + b * N_;
  const float* tyb = ty + b * N_;
  const float* tzb = tz + b * N_;
  __syncthreads();

  // hoist this wave's two Q rows into registers
  float4 q0r[8], q1r[8];
  #pragma unroll
  for (int t = 0; t < 8; t++) {
    q0r[t] = ((const float4*)(sQ + (wave * 2 + 0) * DH_))[t];
    q1r[t] = ((const float4*)(sQ + (wave * 2 + 1) * DH_))[t];
  }

  for (int jc = 0; jc < N_; jc += 64) {
    for (int idx = tid; idx < DH_ * 64; idx += 256) {
      int d = idx >> 6, jj = idx & 63;
      sK[d * 64 + jj] = ktb[(size_t)d * N_ + jc + jj];
    }
    __syncthreads();
    int jj = lane;
    float tjx = txb[jc + jj], tjy = tyb[jc + jj], tjz = tzb[jc + jj];
    float a0 = 0.f, a1 = 0.f;
    #pragma unroll
    for (int t = 0; t < 8; t++) {
      float k0 = sK[(4 * t + 0) * 64 + jj];
      float k1 = sK[(4 * t + 1) * 64 + jj];
      float k2 = sK[(4 * t + 2) * 64 + jj];
      float k3 = sK[(4 * t + 3) * 64 + jj];
      float4 qa = q0r[t], qb = q1r[t];
      a0 = fmaf(qa.x, k0, fmaf(qa.y, k1, fmaf(qa.z, k2, fmaf(qa.w, k3, a0))));
      a1 = fmaf(qb.x, k0, fmaf(qb.y, k1, fmaf(qb.z, k2, fmaf(qb.w, k3, a1))));
    }
    #pragma unroll
    for (int s = 0; s < 2; s++) {
      int ii = wave * 2 + s;
      float a = (s == 0) ? a0 : a1;
      float dx = sti[0][ii] - tjx;
      float dy = sti[1][ii] - tjy;
      float dz = sti[2][ii] - tjz;
      sS[ii][jc + jj] = a * 0.17677669529663689f - (dx * dx + dy * dy + dz * dz);
    }
    __syncthreads();
  }

  #pragma unroll
  for (int s = 0; s < 2; s++) {
    int ii = wave * 2 + s;
    float vrow[6];
    float m = -1e30f;
    #pragma unroll
    for (int t = 0; t < 6; t++) { vrow[t] = sS[ii][t * 64 + lane]; m = fmaxf(m, vrow[t]); }
    #pragma unroll
    for (int off = 32; off >= 1; off >>= 1) m = fmaxf(m, __shfl_xor(m, off, 64));
    float ps = 0.f;
    #pragma unroll
    for (int t = 0; t < 6; t++) {
      float e = expf(vrow[t] - m);
      sS[ii][t * 64 + lane] = e;
      ps += e;
    }
    #pragma unroll
    for (int off = 32; off >= 1; off >>= 1) ps += __shfl_xor(ps, off, 64);
    if (lane == 0) sinv[ii] = 1.0f / ps;
  }
  __syncthreads();

  // ---- PV with row-pair reuse: wave-uniform j-half, each thread owns rows (2p, 2p+1) ----
  // waves 0,1 -> j in [0,192); waves 2,3 -> j in [192,384). Each sV read feeds 2 fmas.
  int jh = wave >> 1;
  int p  = ((wave & 1) << 1) | (lane >> 5);   // row-pair 0..3
  int dd = lane & 31;
  int rA = 2 * p, rB = 2 * p + 1;
  float oA = 0.f, oB = 0.f;
  for (int jc = 0; jc < N_; jc += 64) {
    for (int idx = tid; idx < 64 * DH_; idx += 256) {
      int jj = idx >> 5, d = idx & 31;
      sV[jj * DH_ + d] = vb[(size_t)(jc + jj) * D_ + d];
    }
    __syncthreads();
    if ((jc / 192) == jh) {
      const float* sa = sS[rA] + jc;
      const float* sb = sS[rB] + jc;
      #pragma unroll
      for (int jj = 0; jj < 64; jj += 4) {
        float4 ea = *(const float4*)(sa + jj);
        float4 eb = *(const float4*)(sb + jj);
        float v0 = sV[(jj + 0) * DH_ + dd];
        float v1 = sV[(jj + 1) * DH_ + dd];
        float v2 = sV[(jj + 2) * DH_ + dd];
        float v3 = sV[(jj + 3) * DH_ + dd];
        oA = fmaf(ea.x, v0, fmaf(ea.y, v1, fmaf(ea.z, v2, fmaf(ea.w, v3, oA))));
        oB = fmaf(eb.x, v0, fmaf(eb.y, v1, fmaf(eb.z, v2, fmaf(eb.w, v3, oB))));
      }
    }
    __syncthreads();
  }
  // combine the two j-half partials (reuse sK as scratch; dead after QK)
  float* pr = sK;                  // pr[jh*256 + row*32 + dd]
  pr[jh * 256 + rA * 32 + dd] = oA;
  pr[jh * 256 + rB * 32 + dd] = oB;
  __syncthreads();
  {
    int ii = tid >> 5;
    sQ[tid] = (pr[tid] + pr[256 + tid]) * sinv[ii];   // sQ[ii*32+dd] = ao
  }
  __syncthreads();

  // ---- fused Wo partial: head-slice GEMM + atomics ----
  {
    const float* wo = Wo + (size_t)(h * DH_) * D_ + tid;   // col = tid
    float acc[8];
    #pragma unroll
    for (int r = 0; r < 8; r++) acc[r] = 0.f;
    for (int k = 0; k < DH_; k += 4) {
      float w0 = wo[(size_t)(k + 0) * D_];
      float w1 = wo[(size_t)(k + 1) * D_];
      float w2 = wo[(size_t)(k + 2) * D_];
      float w3 = wo[(size_t)(k + 3) * D_];
      #pragma unroll
      for (int r = 0; r < 8; r++) {
        float4 a4 = *(const float4*)(sQ + r * DH_ + k);
        acc[r] = fmaf(a4.x, w0, fmaf(a4.y, w1, fmaf(a4.z, w2, fmaf(a4.w, w3, acc[r]))));
      }
    }
    float* Sb = S + ((size_t)(b * N_ + i0)) * D_ + tid;
    #pragma unroll
    for (int r = 0; r < 8; r++) atomicAdd(Sb + (size_t)r * D_, acc[r]);
  }
}

// ---------------- fused pair LN-mean + head (shuffle-free pair phase) ----------------
// grid = M, 256 threads
__global__ void pair_head_kernel(const float* __restrict__ projc, const float* __restrict__ projcT,
                                 const float* __restrict__ relc, const float* __restrict__ relcT,
                                 const float* __restrict__ lnw, const float* __restrict__ lnb,
                                 const float* __restrict__ x,
                                 const float* __restrict__ Wf1, const float* __restrict__ bWf1,
                                 const float* __restrict__ Wf2, const float* __restrict__ bWf2,
                                 float* __restrict__ frames, float* __restrict__ tx,
                                 float* __restrict__ ty, float* __restrict__ tz) {
  const int M = B_ * N_;
  int row = blockIdx.x;            // b*N + i
  int b = row / N_;
  int i = row % N_;
  int tid = threadIdx.x;           // 256 = 4 waves
  int lane = tid & 63;
  int wave = tid >> 6;
  __shared__ float svpi[PD_];
  __shared__ float sr[N_];         // rinv per j
  __shared__ float red[4][PD_];
  __shared__ float sfeat[320];
  __shared__ float fred[2][128];
  __shared__ float sg[128];
  __shared__ float sraw[9];

  if (tid < PD_) svpi[tid] = projc[row * PD_ + tid];
  if (tid < D_) sfeat[tid] = x[(size_t)row * D_ + tid];
  __syncthreads();

  // ---- pass A: rinv[j] via thread-per-j (coalesced transposed reads, no shuffles) ----
  {
    int jA = tid;                  // 0..255
    int raA = jA - i; raA = raA < -64 ? -64 : (raA > 64 ? 64 : raA); raA += 64;
    const float* pA = projcT + b * N_ + jA;
    const float* rA = relcT + raA;
    float s2A = 0.f;
    #pragma unroll 8
    for (int c = 0; c < PD_; c++) {
      float dA = svpi[c] + pA[(size_t)c * M] + rA[c * RT_];
      s2A = fmaf(dA, dA, s2A);
    }
    sr[jA] = rsqrtf(s2A * (1.0f / PD_) + 1e-5f);
    if (tid < 128) {
      int jB = tid + 256;          // 256..383
      int raB = jB - i; raB = raB < -64 ? -64 : (raB > 64 ? 64 : raB); raB += 64;
      const float* pB = projcT + b * N_ + jB;
      const float* rB = relcT + raB;
      float s2B = 0.f;
      #pragma unroll 8
      for (int c = 0; c < PD_; c++) {
        float dB = svpi[c] + pB[(size_t)c * M] + rB[c * RT_];
        s2B = fmaf(dB, dB, s2B);
      }
      sr[jB] = rsqrtf(s2B * (1.0f / PD_) + 1e-5f);
    }
  }
  __syncthreads();

  // ---- pass B: per-channel accumulation (row-major coalesced, no shuffles) ----
  {
    float vpl = svpi[lane];
    const float* pb = projc + (size_t)b * N_ * PD_;
    float acc = 0.0f;
    for (int j = wave * 2; j < N_; j += 8) {
      int ja = j, jb = j + 1;
      int ra = ja - i; ra = ra < -64 ? -64 : (ra > 64 ? 64 : ra); ra += 64;
      int rb = jb - i; rb = rb < -64 ? -64 : (rb > 64 ? 64 : rb); rb += 64;
      float da = vpl + pb[ja * PD_ + lane] + relc[ra * PD_ + lane];
      float db = vpl + pb[jb * PD_ + lane] + relc[rb * PD_ + lane];
      acc = fmaf(da, sr[ja], fmaf(db, sr[jb], acc));
    }
    red[wave][lane] = acc;
  }
  __syncthreads();
  if (wave == 0) {
    float s = red[0][lane] + red[1][lane] + red[2][lane] + red[3][lane];
    sfeat[D_ + lane] = lnb[lane] + s * lnw[lane] * (1.0f / N_);
  }
  __syncthreads();

  // ---- fc1 silu (320 -> 128), 2 k-chunks x 128 cols ----
  int kc = tid >> 7, c = tid & 127;
  int koff = kc * 160;
  const float* wp = Wf1 + (size_t)koff * 128 + c;
  const float* s0 = sfeat + koff;
  float a0 = 0.f, a1 = 0.f, a2 = 0.f, a3 = 0.f;
  for (int kk = 0; kk < 160; kk += 4) {
    a0 = fmaf(s0[kk],     wp[(size_t)kk * 128],       a0);
    a1 = fmaf(s0[kk + 1], wp[(size_t)(kk + 1) * 128], a1);
    a2 = fmaf(s0[kk + 2], wp[(size_t)(kk + 2) * 128], a2);
    a3 = fmaf(s0[kk + 3], wp[(size_t)(kk + 3) * 128], a3);
  }
  fred[kc][c] = (a0 + a1) + (a2 + a3);
  __syncthreads();
  if (tid < 128) {
    float g = fred[0][tid] + fred[1][tid] + bWf1[tid];
    sg[tid] = g / (1.0f + expf(-g));
  }
  __syncthreads();

  // ---- fc2 (128 -> 9), rot6d, frame write ----
  if (tid < 9) {
    float b0 = 0.f, b1v = 0.f;
    for (int kk = 0; kk < 128; kk += 2) {
      b0  = fmaf(sg[kk],     Wf2[(kk)     * 9 + tid], b0);
      b1v = fmaf(sg[kk + 1], Wf2[(kk + 1) * 9 + tid], b1v);
    }
    sraw[tid] = bWf2[tid] + b0 + b1v;
  }
  __syncthreads();
  if (tid == 0) {
    float a1x = sraw[0], a1y = sraw[1], a1z = sraw[2];
    float a2x = sraw[3], a2y = sraw[4], a2z = sraw[5];
    float n1 = sqrtf(a1x * a1x + a1y * a1y + a1z * a1z + 1e-8f);
    float b1x = a1x / n1, b1y = a1y / n1, b1z = a1z / n1;
    float dp = b1x * a2x + b1y * a2y + b1z * a2z;
    float px = a2x - dp * b1x, py = a2y - dp * b1y, pz = a2z - dp * b1z;
    float n2 = sqrtf(px * px + py * py + pz * pz + 1e-8f);
    float b2x = px / n2, b2y = py / n2, b2z = pz / n2;
    float b3x = b1y * b2z - b1z * b2y;
    float b3y = b1z * b2x - b1x * b2z;
    float b3z = b1x * b2y - b1y * b2x;
    float* f = frames + row * 16;
    f[0]  = b1x; f[1]  = b1y; f[2]  = b1z; f[3]  = sraw[6];
    f[4]  = b2x; f[5]  = b2y; f[6]  = b2z; f[7]  = sraw[7];
    f[8]  = b3x; f[9]  = b3y; f[10] = b3z; f[11] = sraw[8];
    f[12] = 0.0f; f[13] = 0.0f; f[14] = 0.0f; f[15] = 1.0f;
    tx[row] = sraw[6];
    ty[row] = sraw[7];
    tz[row] = sraw[8];
  }
}

// ---------------- output ----------------
__global__ void write_out_kernel(const float* __restrict__ frames, const float* __restrict__ x,
                                 float* __restrict__ out) {
  int i = blockIdx.x * 256 + threadIdx.x;
  const int nf = B_ * N_ * 16;
  const int total = nf + B_ * N_ * D_;
  if (i < nf) out[i] = frames[i];
  else if (i < total) out[i] = x[i - nf];
}

extern "C" void kernel_launch(void* const* d_in, const int* in_sizes, int n_in,
                              void* d_out, int out_size, void* d_ws, size_t ws_size,
                              hipStream_t stream) {
  const int*   tokens    = (const int*)  d_in[0];
  const float* tok_emb   = (const float*)d_in[1];
  const float* emb_ln_w  = (const float*)d_in[2];
  const float* emb_ln_b  = (const float*)d_in[3];
  const float* Wq        = (const float*)d_in[4];
  const float* Wk        = (const float*)d_in[5];
  const float* Wv        = (const float*)d_in[6];
  const float* Wo        = (const float*)d_in[7];
  const float* bo        = (const float*)d_in[8];
  const float* attn_ln_w = (const float*)d_in[9];
  const float* attn_ln_b = (const float*)d_in[10];
  const float* ff_ln_w   = (const float*)d_in[11];
  const float* ff_ln_b   = (const float*)d_in[12];
  const float* W1        = (const float*)d_in[13];
  const float* b1        = (const float*)d_in[14];
  const float* W2        = (const float*)d_in[15];
  const float* b2        = (const float*)d_in[16];
  const float* Wop       = (const float*)d_in[17];
  const float* bop       = (const float*)d_in[18];
  const float* relpos    = (const float*)d_in[19];
  const float* pair_ln_w = (const float*)d_in[20];
  const float* pair_ln_b = (const float*)d_in[21];
  const float* Wf1       = (const float*)d_in[22];
  const float* bWf1      = (const float*)d_in[23];
  const float* Wf2       = (const float*)d_in[24];
  const float* bWf2      = (const float*)d_in[25];

  const int M = B_ * N_;           // 768
  const int XE = M * D_;           // 196608
  float* ws     = (float*)d_ws;
  float* frames = ws;                      // 12288
  float* projc  = frames + M * 16;         // 49152
  float* projcT = projc  + M * PD_;        // 49152
  float* relc   = projcT + M * PD_;        // 8256 (pad 8320)
  float* relcT  = relc   + 8320;           // 64*132 = 8448
  float* tx     = relcT  + 8448;           // 768
  float* ty     = tx     + M;              // 768
  float* tz     = ty     + M;              // 768
  float* xA     = tz     + M;              // XE  (state ping)
  float* xB     = xA + XE;                 // XE  (state pong)
  float* q      = xB + XE;                 // XE
  float* kt     = q  + XE;                 // XE (K transposed [b,h,d,j])
  float* v      = kt + XE;                 // XE

  prologue_kernel<<<M, 256, 0, stream>>>(tokens, tok_emb, emb_ln_w, emb_ln_b, relpos,
                                         xA, frames, tx, ty, tz, relc, relcT, xB);
  qkv_kernel<<<(M / GR) * 12, 256, 0, stream>>>(xA, Wq, Wk, Wv, q, kt, v);

  for (int l = 0; l < L_; l++) {
    float* Sin  = (l & 1) ? xB : xA;       // holds x_l; attn accumulates ao@Wo into it
    float* Sout = (l & 1) ? xA : xB;       // pre-zeroed; ff accumulates new state
    attn_kernel<<<B_ * H_ * (N_ / IT), 256, 0, stream>>>(
        q, kt, v, tx, ty, tz, Wo + (size_t)l * D_ * D_, Sin);
    ff_fused_kernel<<<(M / GR) * 8, 256, 0, stream>>>(
        Sin, bo + l * D_,
        attn_ln_w + l * D_, attn_ln_b + l * D_,
        ff_ln_w + l * D_, ff_ln_b + l * D_,
        W1 + (size_t)l * D_ * 1024, b1 + l * 1024,
        W2 + (size_t)l * 1024 * D_, b2 + l * D_, Sout);
    if (l < L_ - 1) {
      int lq = l + 1;
      proj_qkv_kernel<<<M + (M / GR) * 12, 256, 0, stream>>>(
          Sout, Wop, bop, projc, projcT,
          Wq + (size_t)lq * D_ * D_, Wk + (size_t)lq * D_ * D_, Wv + (size_t)lq * D_ * D_,
          q, kt, v, Sin);
    } else {
      proj_qkv_kernel<<<M, 256, 0, stream>>>(Sout, Wop, bop, projc, projcT,
                                             Wq, Wk, Wv, q, kt, v, Sin);
    }
    pair_head_kernel<<<M, 256, 0, stream>>>(projc, projcT, relc, relcT, pair_ln_w, pair_ln_b,
                                            Sout, Wf1, bWf1, Wf2, bWf2, frames, tx, ty, tz);
  }

  // L_=8 layers: final state lands in xA
  const int total = B_ * N_ * 16 + B_ * N_ * D_;
  write_out_kernel<<<(total + 255) / 256, 256, 0, stream>>>(frames, xA, (float*)d_out);
}

// Round 14
// 847.660 us; speedup vs baseline: 1.1566x; 1.0205x over previous
//
#include <hip/hip_runtime.h>
#include <hip/hip_bf16.h>
#include <math.h>

#define B_  2
#define N_  384
#define D_  256
#define PD_ 64
#define L_  8
#define H_  8
#define DH_ 32
#define GR  4      // rows per GEMM block
#define IT  8      // attention i-tile
#define RT_ 132    // relcT row stride (129 padded)

// ---------------- prologue: embed+LN, frames/t init, centered relpos, zero ff-target ------------
// grid = M, 256 threads
__global__ void prologue_kernel(const int* __restrict__ tokens, const float* __restrict__ tok_emb,
                                const float* __restrict__ lnw, const float* __restrict__ lnb,
                                const float* __restrict__ relpos,
                                float* __restrict__ x, float* __restrict__ frames,
                                float* __restrict__ tx, float* __restrict__ ty,
                                float* __restrict__ tz,
                                float* __restrict__ relc, float* __restrict__ relcT,
                                float* __restrict__ xz) {
  int row = blockIdx.x;            // b*N + n
  int n = row % N_;
  int d = threadIdx.x;             // 0..255
  __shared__ float rbuf[256];
  __shared__ float smr;
  if (d < 16) frames[row * 16 + d] = (d == 0 || d == 5 || d == 10 || d == 15) ? 1.0f : 0.0f;
  if (d == 16) tx[row] = 0.0f;
  if (d == 17) ty[row] = 0.0f;
  if (d == 18) tz[row] = 0.0f;
  xz[(size_t)row * D_ + d] = 0.0f;          // zero layer-0 ff accumulation target
  // rel row mean (blocks 0..128, wave 3)
  if (row < 129 && d >= 192) {
    int lane = d & 63;
    float s = relpos[row * PD_ + lane];
    #pragma unroll
    for (int off = 32; off >= 1; off >>= 1) s += __shfl_xor(s, off, 64);
    if (lane == 0) smr = s * (1.0f / PD_);
  }
  // embed + pos-enc + LN
  int tok = tokens[row];
  float val = tok_emb[tok * D_ + d];
  int i = d >> 1;
  float dv = expf((float)(2 * i) * (-logf(10000.0f) / (float)D_));
  float ang = (float)n * dv;
  val += (d & 1) ? cosf(ang) : sinf(ang);
  rbuf[d] = val; __syncthreads();          // smr visible after this
  for (int s = 128; s > 0; s >>= 1) { if (d < s) rbuf[d] += rbuf[d + s]; __syncthreads(); }
  float mean = rbuf[0] / D_;
  __syncthreads();
  rbuf[d] = val * val; __syncthreads();
  for (int s = 128; s > 0; s >>= 1) { if (d < s) rbuf[d] += rbuf[d + s]; __syncthreads(); }
  float var = rbuf[0] / D_ - mean * mean;
  float r = rsqrtf(var + 1e-5f);
  x[row * D_ + d] = (val - mean) * r * lnw[d] + lnb[d];
  // centered relpos + transpose
  if (row < 129 && d < PD_) {
    float cv = relpos[row * PD_ + d] - smr;
    relc[row * PD_ + d] = cv;
    relcT[d * RT_ + row] = cv;
  }
}

// ---------------- qkv unit (GR=4, 8 k-chunks x 32 col-threads, 2 cols/thread; K transposed) ----
// Same grid/threads/fma/global-loads as before; LDS b128 issues halved (64 -> 32 per thread).
__device__ __forceinline__ void qkv_unit(int bid, int tid, const float* __restrict__ x,
                                         const float* __restrict__ Wq, const float* __restrict__ Wk,
                                         const float* __restrict__ Wv,
                                         float* __restrict__ q, float* __restrict__ kt,
                                         float* __restrict__ v, float* sA) {
  int tile = bid & 3;
  int m = (bid >> 2) % 3;
  int r0 = (bid / 12) * GR;
  float* red = sA + GR * D_;       // 2048 floats (8 kc x 4 rows x 64 cols)
  {
    int r = tid >> 6, lane = tid & 63;
    ((float4*)(sA + r * D_))[lane] = ((const float4*)(x + (size_t)(r0 + r) * D_))[lane];
  }
  __syncthreads();
  const float* W = (m == 0) ? Wq : (m == 1) ? Wk : Wv;
  int kc = tid >> 5, c = tid & 31;     // 8 k-chunks (32-k each) x 32 col-threads (cols c, c+32)
  const float* wp = W + (size_t)(kc * 32) * D_ + tile * 64 + c;
  const float* s0 = sA + kc * 32;
  float a0 = 0.f, a1 = 0.f, a2 = 0.f, a3 = 0.f;   // col c
  float b0 = 0.f, b1 = 0.f, b2 = 0.f, b3 = 0.f;   // col c+32
  for (int kk = 0; kk < 32; kk += 4) {
    float w0 = wp[(size_t)kk * D_],       w1 = wp[(size_t)(kk + 1) * D_];
    float w2 = wp[(size_t)(kk + 2) * D_], w3 = wp[(size_t)(kk + 3) * D_];
    float u0 = wp[(size_t)kk * D_ + 32],       u1 = wp[(size_t)(kk + 1) * D_ + 32];
    float u2 = wp[(size_t)(kk + 2) * D_ + 32], u3 = wp[(size_t)(kk + 3) * D_ + 32];
    float4 h0 = *(const float4*)(s0 + 0 * D_ + kk);
    float4 h1 = *(const float4*)(s0 + 1 * D_ + kk);
    float4 h2 = *(const float4*)(s0 + 2 * D_ + kk);
    float4 h3 = *(const float4*)(s0 + 3 * D_ + kk);
    a0 = fmaf(h0.x, w0, fmaf(h0.y, w1, fmaf(h0.z, w2, fmaf(h0.w, w3, a0))));
    a1 = fmaf(h1.x, w0, fmaf(h1.y, w1, fmaf(h1.z, w2, fmaf(h1.w, w3, a1))));
    a2 = fmaf(h2.x, w0, fmaf(h2.y, w1, fmaf(h2.z, w2, fmaf(h2.w, w3, a2))));
    a3 = fmaf(h3.x, w0, fmaf(h3.y, w1, fmaf(h3.z, w2, fmaf(h3.w, w3, a3))));
    b0 = fmaf(h0.x, u0, fmaf(h0.y, u1, fmaf(h0.z, u2, fmaf(h0.w, u3, b0))));
    b1 = fmaf(h1.x, u0, fmaf(h1.y, u1, fmaf(h1.z, u2, fmaf(h1.w, u3, b1))));
    b2 = fmaf(h2.x, u0, fmaf(h2.y, u1, fmaf(h2.z, u2, fmaf(h2.w, u3, b2))));
    b3 = fmaf(h3.x, u0, fmaf(h3.y, u1, fmaf(h3.z, u2, fmaf(h3.w, u3, b3))));
  }
  red[(kc * 4 + 0) * 64 + c] = a0;
  red[(kc * 4 + 1) * 64 + c] = a1;
  red[(kc * 4 + 2) * 64 + c] = a2;
  red[(kc * 4 + 3) * 64 + c] = a3;
  red[(kc * 4 + 0) * 64 + 32 + c] = b0;
  red[(kc * 4 + 1) * 64 + 32 + c] = b1;
  red[(kc * 4 + 2) * 64 + 32 + c] = b2;
  red[(kc * 4 + 3) * 64 + 32 + c] = b3;
  __syncthreads();
  int r = tid >> 6, c64 = tid & 63;
  float s = 0.f;
  #pragma unroll
  for (int k8 = 0; k8 < 8; k8++) s += red[(k8 * 4 + r) * 64 + c64];
  int col = tile * 64 + c64;
  int row = r0 + r;
  if (m == 1) {
    int b = row / N_, j = row % N_;
    int hh = col >> 5, dd = col & 31;
    kt[((size_t)(b * H_ + hh) * DH_ + dd) * N_ + j] = s;
  } else {
    float* O = (m == 0) ? q : v;
    O[(size_t)row * D_ + col] = s;
  }
}

// ---------------- proj unit: centered relu(x@Wop+bop) -> projc (+transposed); zero zbuf row ----
__device__ __forceinline__ void proj_unit(int row, int tid, const float* __restrict__ x,
                                          const float* __restrict__ Wop, const float* __restrict__ bop,
                                          float* __restrict__ projc, float* __restrict__ projcT,
                                          float* __restrict__ zbuf, float* smem) {
  float* sA  = smem;               // 256
  float* red = smem + 256;         // 256
  zbuf[(size_t)row * D_ + tid] = 0.0f;     // zero next ff accumulation target
  if (tid < 64) ((float4*)sA)[tid] = ((const float4*)(x + (size_t)row * D_))[tid];
  __syncthreads();
  int kc = tid >> 6, c = tid & 63;
  const float* wp = Wop + (kc * 64) * PD_ + c;
  const float* s0 = sA + kc * 64;
  float a0 = 0.f, a1 = 0.f, a2 = 0.f, a3 = 0.f;
  for (int kk = 0; kk < 64; kk += 4) {
    a0 = fmaf(s0[kk],     wp[(kk)     * PD_], a0);
    a1 = fmaf(s0[kk + 1], wp[(kk + 1) * PD_], a1);
    a2 = fmaf(s0[kk + 2], wp[(kk + 2) * PD_], a2);
    a3 = fmaf(s0[kk + 3], wp[(kk + 3) * PD_], a3);
  }
  red[kc * 64 + c] = (a0 + a1) + (a2 + a3);
  __syncthreads();
  if (tid < 64) {
    float acc = fmaxf(bop[tid] + red[tid] + red[64 + tid] + red[128 + tid] + red[192 + tid], 0.0f);
    float s = acc;
    #pragma unroll
    for (int off = 32; off >= 1; off >>= 1) s += __shfl_xor(s, off, 64);
    float cv = acc - s * (1.0f / PD_);
    projc[row * PD_ + tid] = cv;
    projcT[(size_t)tid * (B_ * N_) + row] = cv;
  }
}

// ---------------- standalone qkv (layer 0) ----------------
__global__ void qkv_kernel(const float* __restrict__ x, const float* __restrict__ Wq,
                           const float* __restrict__ Wk, const float* __restrict__ Wv,
                           float* __restrict__ q, float* __restrict__ kt, float* __restrict__ v) {
  __shared__ __align__(16) float smem[GR * D_ + 2048];
  qkv_unit(blockIdx.x, threadIdx.x, x, Wq, Wk, Wv, q, kt, v, smem);
}

// ---------------- combined proj(l) + qkv(l+1): both read only x ----------------
__global__ void proj_qkv_kernel(const float* __restrict__ x,
                                const float* __restrict__ Wop, const float* __restrict__ bop,
                                float* __restrict__ projc, float* __restrict__ projcT,
                                const float* __restrict__ Wq, const float* __restrict__ Wk,
                                const float* __restrict__ Wv,
                                float* __restrict__ q, float* __restrict__ kt,
                                float* __restrict__ v, float* __restrict__ zbuf) {
  __shared__ __align__(16) float smem[GR * D_ + 2048];
  int bid = blockIdx.x, tid = threadIdx.x;
  if (bid < B_ * N_) proj_unit(bid, tid, x, Wop, bop, projc, projcT, zbuf, smem);
  else               qkv_unit(bid - B_ * N_, tid, x, Wq, Wk, Wv, q, kt, v, smem);
}

// ---------------- fused FF: T += x + b2 + gelu(ffLN(x)@W1+b1)@W2, x = attnLN(S + bo) -----------
// grid = (M/GR)*8 = 1536, 256 threads. W1 phase: 4 k-chunks x 64 col-threads, 2 cols/thread
// (same grid/fma/global-loads; LDS b128 issues halved 128 -> 64 per thread).
__global__ void ff_fused_kernel(const float* __restrict__ S, const float* __restrict__ bo,
                                const float* __restrict__ alnw, const float* __restrict__ alnb,
                                const float* __restrict__ flnw, const float* __restrict__ flnb,
                                const float* __restrict__ W1, const float* __restrict__ b1,
                                const float* __restrict__ W2, const float* __restrict__ b2v,
                                float* __restrict__ T) {
  int bid = blockIdx.x;
  int tile = bid & 7;              // 128 f-cols each
  int r0 = (bid >> 3) * GR;
  int tid = threadIdx.x;
  __shared__ __align__(16) float sA[GR * D_];       // ff-LN'd h rows (4 KB)
  __shared__ __align__(16) float sX[GR * D_];       // attn-LN'd x rows (4 KB)
  __shared__ float red[4 * GR * 128];               // split-k partials (8 KB)
  __shared__ __align__(16) float sF[128 * 4];       // f tile [k][r] (2 KB)
  {
    int r = tid >> 6, lane = tid & 63;
    float4 v = ((const float4*)(S + (size_t)(r0 + r) * D_))[lane];
    float4 bo4 = ((const float4*)bo)[lane];
    v.x += bo4.x; v.y += bo4.y; v.z += bo4.z; v.w += bo4.w;
    // attn LN
    float s = v.x + v.y + v.z + v.w;
    float s2 = v.x * v.x + v.y * v.y + v.z * v.z + v.w * v.w;
    #pragma unroll
    for (int off = 32; off >= 1; off >>= 1) {
      s  += __shfl_xor(s, off, 64);
      s2 += __shfl_xor(s2, off, 64);
    }
    float mean = s * (1.0f / D_);
    float var = s2 * (1.0f / D_) - mean * mean;
    float rin = rsqrtf(var + 1e-5f);
    float4 aw = ((const float4*)alnw)[lane];
    float4 ab = ((const float4*)alnb)[lane];
    float4 x4;
    x4.x = (v.x - mean) * rin * aw.x + ab.x;
    x4.y = (v.y - mean) * rin * aw.y + ab.y;
    x4.z = (v.z - mean) * rin * aw.z + ab.z;
    x4.w = (v.w - mean) * rin * aw.w + ab.w;
    ((float4*)(sX + r * D_))[lane] = x4;
    // ff LN
    float t = x4.x + x4.y + x4.z + x4.w;
    float t2 = x4.x * x4.x + x4.y * x4.y + x4.z * x4.z + x4.w * x4.w;
    #pragma unroll
    for (int off = 32; off >= 1; off >>= 1) {
      t  += __shfl_xor(t, off, 64);
      t2 += __shfl_xor(t2, off, 64);
    }
    float mean2 = t * (1.0f / D_);
    float var2 = t2 * (1.0f / D_) - mean2 * mean2;
    float rin2 = rsqrtf(var2 + 1e-5f);
    float4 fw = ((const float4*)flnw)[lane];
    float4 fb = ((const float4*)flnb)[lane];
    float4 h4;
    h4.x = (x4.x - mean2) * rin2 * fw.x + fb.x;
    h4.y = (x4.y - mean2) * rin2 * fw.y + fb.y;
    h4.z = (x4.z - mean2) * rin2 * fw.z + fb.z;
    h4.w = (x4.w - mean2) * rin2 * fw.w + fb.w;
    ((float4*)(sA + r * D_))[lane] = h4;
  }
  __syncthreads();
  // ---- W1 GEMM: 4 k-chunks (64-k) x 64 col-threads, cols c and c+64 ----
  {
    int kc = tid >> 6, c = tid & 63;
    int col = tile * 128 + c;
    const float* wp = W1 + (size_t)(kc * 64) * 1024 + col;
    const float* s0 = sA + kc * 64;
    float a0 = 0.f, a1 = 0.f, a2 = 0.f, a3 = 0.f;   // col c
    float b0 = 0.f, b1v = 0.f, b2 = 0.f, b3 = 0.f;  // col c+64
    for (int kk = 0; kk < 64; kk += 4) {
      float w0 = wp[(size_t)kk * 1024],       w1 = wp[(size_t)(kk + 1) * 1024];
      float w2 = wp[(size_t)(kk + 2) * 1024], w3 = wp[(size_t)(kk + 3) * 1024];
      float u0 = wp[(size_t)kk * 1024 + 64],       u1 = wp[(size_t)(kk + 1) * 1024 + 64];
      float u2 = wp[(size_t)(kk + 2) * 1024 + 64], u3 = wp[(size_t)(kk + 3) * 1024 + 64];
      float4 h0 = *(const float4*)(s0 + 0 * D_ + kk);
      float4 h1 = *(const float4*)(s0 + 1 * D_ + kk);
      float4 h2 = *(const float4*)(s0 + 2 * D_ + kk);
      float4 h3 = *(const float4*)(s0 + 3 * D_ + kk);
      a0  = fmaf(h0.x, w0, fmaf(h0.y, w1, fmaf(h0.z, w2, fmaf(h0.w, w3, a0))));
      a1  = fmaf(h1.x, w0, fmaf(h1.y, w1, fmaf(h1.z, w2, fmaf(h1.w, w3, a1))));
      a2  = fmaf(h2.x, w0, fmaf(h2.y, w1, fmaf(h2.z, w2, fmaf(h2.w, w3, a2))));
      a3  = fmaf(h3.x, w0, fmaf(h3.y, w1, fmaf(h3.z, w2, fmaf(h3.w, w3, a3))));
      b0  = fmaf(h0.x, u0, fmaf(h0.y, u1, fmaf(h0.z, u2, fmaf(h0.w, u3, b0))));
      b1v = fmaf(h1.x, u0, fmaf(h1.y, u1, fmaf(h1.z, u2, fmaf(h1.w, u3, b1v))));
      b2  = fmaf(h2.x, u0, fmaf(h2.y, u1, fmaf(h2.z, u2, fmaf(h2.w, u3, b2))));
      b3  = fmaf(h3.x, u0, fmaf(h3.y, u1, fmaf(h3.z, u2, fmaf(h3.w, u3, b3))));
    }
    red[(kc * 4 + 0) * 128 + c] = a0;
    red[(kc * 4 + 1) * 128 + c] = a1;
    red[(kc * 4 + 2) * 128 + c] = a2;
    red[(kc * 4 + 3) * 128 + c] = a3;
    red[(kc * 4 + 0) * 128 + 64 + c] = b0;
    red[(kc * 4 + 1) * 128 + 64 + c] = b1v;
    red[(kc * 4 + 2) * 128 + 64 + c] = b2;
    red[(kc * 4 + 3) * 128 + 64 + c] = b3;
  }
  __syncthreads();
  // ---- gelu, f tile to LDS [k][r] (sum 4 split-k partials) ----
  {
    int rA = tid >> 7, c = tid & 127;
    int col = tile * 128 + c;
    #pragma unroll
    for (int p = 0; p < 2; p++) {
      int r = rA + p * 2;
      float s = red[(0 * 4 + r) * 128 + c] + red[(1 * 4 + r) * 128 + c]
              + red[(2 * 4 + r) * 128 + c] + red[(3 * 4 + r) * 128 + c] + b1[col];
      s = 0.5f * s * (1.0f + erff(s * 0.7071067811865475f));
      sF[c * 4 + r] = s;
    }
  }
  __syncthreads();
  // ---- W2 partial (128 k-slice x 256 out-cols), atomic accumulate ----
  {
    const float* w2p = W2 + (size_t)(tile * 128) * D_ + tid;
    float o0 = 0.f, o1 = 0.f, o2 = 0.f, o3 = 0.f;
    #pragma unroll 8
    for (int k = 0; k < 128; k++) {
      float w = w2p[(size_t)k * D_];
      float4 f4 = *(const float4*)(sF + k * 4);
      o0 = fmaf(f4.x, w, o0); o1 = fmaf(f4.y, w, o1);
      o2 = fmaf(f4.z, w, o2); o3 = fmaf(f4.w, w, o3);
    }
    if (tile == 0) {
      float bb2 = b2v[tid];
      o0 += sX[0 * D_ + tid] + bb2;
      o1 += sX[1 * D_ + tid] + bb2;
      o2 += sX[2 * D_ + tid] + bb2;
      o3 += sX[3 * D_ + tid] + bb2;
    }
    atomicAdd(&T[(size_t)(r0 + 0) * D_ + tid], o0);
    atomicAdd(&T[(size_t)(r0 + 1) * D_ + tid], o1);
    atomicAdd(&T[(size_t)(r0 + 2) * D_ + tid], o2);
    atomicAdd(&T[(size_t)(r0 + 3) * D_ + tid], o3);
  }
}

// ---------------- attention (staged, XCD-swizzled, PV row-pair reuse) + fused Wo partial --------
// grid = 768, 256 threads. Block remap: each XCD owns 2 heads x 48 tiles (K/V stay in its L2).
__global__ void attn_kernel(const float* __restrict__ Q, const float* __restrict__ KT,
                            const float* __restrict__ V,
                            const float* __restrict__ tx, const float* __restrict__ ty,
                            const float* __restrict__ tz,
                            const float* __restrict__ Wo, float* __restrict__ S) {
  // XCD-aware remap: wgid%8 = XCD (typical assignment); give each XCD 2 whole heads.
  int wgid = blockIdx.x;
  int xcd  = wgid & 7;
  int slot = wgid >> 3;            // 0..95
  int head = xcd * 2 + (slot / 48);// 0..15 == b*H + h
  int it   = slot % 48;
  int h = head & 7;
  int b = head >> 3;
  int i0 = it * IT;
  int tid = threadIdx.x;
  int wave = tid >> 6, lane = tid & 63;

  __shared__ __align__(16) float sQ[IT * DH_];
  __shared__ __align__(16) float sK[DH_ * 64];
  __shared__ __align__(16) float sV[64 * DH_];
  __shared__ __align__(16) float sS[IT][N_];
  __shared__ float sti[3][IT];
  __shared__ float sinv[IT];

  {
    int ii = tid >> 5, d = tid & 31;
    sQ[ii * DH_ + d] = Q[((size_t)(b * N_ + i0 + ii)) * D_ + h * DH_ + d];
  }
  if (tid < IT) {
    sti[0][tid] = tx[b * N_ + i0 + tid];
    sti[1][tid] = ty[b * N_ + i0 + tid];
    sti[2][tid] = tz[b * N_ + i0 + tid];
  }
  const float* ktb = KT + (size_t)(b * H_ + h) * DH_ * N_;
  const float* vb  = V + (size_t)b * N_ * D_ + h * DH_;
  const float* txb = tx + b * N_;
  const float* tyb = ty + b * N_;
  const float* tzb = tz + b * N_;
  __syncthreads();

  // hoist this wave's two Q rows into registers
  float4 q0r[8], q1r[8];
  #pragma unroll
  for (int t = 0; t < 8; t++) {
    q0r[t] = ((const float4*)(sQ + (wave * 2 + 0) * DH_))[t];
    q1r[t] = ((const float4*)(sQ + (wave * 2 + 1) * DH_))[t];
  }

  for (int jc = 0; jc < N_; jc += 64) {
    for (int idx = tid; idx < DH_ * 64; idx += 256) {
      int d = idx >> 6, jj = idx & 63;
      sK[d * 64 + jj] = ktb[(size_t)d * N_ + jc + jj];
    }
    __syncthreads();
    int jj = lane;
    float tjx = txb[jc + jj], tjy = tyb[jc + jj], tjz = tzb[jc + jj];
    float a0 = 0.f, a1 = 0.f;
    #pragma unroll
    for (int t = 0; t < 8; t++) {
      float k0 = sK[(4 * t + 0) * 64 + jj];
      float k1 = sK[(4 * t + 1) * 64 + jj];
      float k2 = sK[(4 * t + 2) * 64 + jj];
      float k3 = sK[(4 * t + 3) * 64 + jj];
      float4 qa = q0r[t], qb = q1r[t];
      a0 = fmaf(qa.x, k0, fmaf(qa.y, k1, fmaf(qa.z, k2, fmaf(qa.w, k3, a0))));
      a1 = fmaf(qb.x, k0, fmaf(qb.y, k1, fmaf(qb.z, k2, fmaf(qb.w, k3, a1))));
    }
    #pragma unroll
    for (int s = 0; s < 2; s++) {
      int ii = wave * 2 + s;
      float a = (s == 0) ? a0 : a1;
      float dx = sti[0][ii] - tjx;
      float dy = sti[1][ii] - tjy;
      float dz = sti[2][ii] - tjz;
      sS[ii][jc + jj] = a * 0.17677669529663689f - (dx * dx + dy * dy + dz * dz);
    }
    __syncthreads();
  }

  #pragma unroll
  for (int s = 0; s < 2; s++) {
    int ii = wave * 2 + s;
    float vrow[6];
    float m = -1e30f;
    #pragma unroll
    for (int t = 0; t < 6; t++) { vrow[t] = sS[ii][t * 64 + lane]; m = fmaxf(m, vrow[t]); }
    #pragma unroll
    for (int off = 32; off >= 1; off >>= 1) m = fmaxf(m, __shfl_xor(m, off, 64));
    float ps = 0.f;
    #pragma unroll
    for (int t = 0; t < 6; t++) {
      float e = expf(vrow[t] - m);
      sS[ii][t * 64 + lane] = e;
      ps += e;
    }
    #pragma unroll
    for (int off = 32; off >= 1; off >>= 1) ps += __shfl_xor(ps, off, 64);
    if (lane == 0) sinv[ii] = 1.0f / ps;
  }
  __syncthreads();

  // ---- PV with row-pair reuse: wave-uniform j-half, each thread owns rows (2p, 2p+1) ----
  // waves 0,1 -> j in [0,192); waves 2,3 -> j in [192,384). Each sV read feeds 2 fmas.
  int jh = wave >> 1;
  int p  = ((wave & 1) << 1) | (lane >> 5);   // row-pair 0..3
  int dd = lane & 31;
  int rA = 2 * p, rB = 2 * p + 1;
  float oA = 0.f, oB = 0.f;
  for (int jc = 0; jc < N_; jc += 64) {
    for (int idx = tid; idx < 64 * DH_; idx += 256) {
      int jj = idx >> 5, d = idx & 31;
      sV[jj * DH_ + d] = vb[(size_t)(jc + jj) * D_ + d];
    }
    __syncthreads();
    if ((jc / 192) == jh) {
      const float* sa = sS[rA] + jc;
      const float* sb = sS[rB] + jc;
      #pragma unroll
      for (int jj = 0; jj < 64; jj += 4) {
        float4 ea = *(const float4*)(sa + jj);
        float4 eb = *(const float4*)(sb + jj);
        float v0 = sV[(jj + 0) * DH_ + dd];
        float v1 = sV[(jj + 1) * DH_ + dd];
        float v2 = sV[(jj + 2) * DH_ + dd];
        float v3 = sV[(jj + 3) * DH_ + dd];
        oA = fmaf(ea.x, v0, fmaf(ea.y, v1, fmaf(ea.z, v2, fmaf(ea.w, v3, oA))));
        oB = fmaf(eb.x, v0, fmaf(eb.y, v1, fmaf(eb.z, v2, fmaf(eb.w, v3, oB))));
      }
    }
    __syncthreads();
  }
  // combine the two j-half partials (reuse sK as scratch; dead after QK)
  float* pr = sK;                  // pr[jh*256 + row*32 + dd]
  pr[jh * 256 + rA * 32 + dd] = oA;
  pr[jh * 256 + rB * 32 + dd] = oB;
  __syncthreads();
  {
    int ii = tid >> 5;
    sQ[tid] = (pr[tid] + pr[256 + tid]) * sinv[ii];   // sQ[ii*32+dd] = ao
  }
  __syncthreads();

  // ---- fused Wo partial: head-slice GEMM + atomics ----
  {
    const float* wo = Wo + (size_t)(h * DH_) * D_ + tid;   // col = tid
    float acc[8];
    #pragma unroll
    for (int r = 0; r < 8; r++) acc[r] = 0.f;
    for (int k = 0; k < DH_; k += 4) {
      float w0 = wo[(size_t)(k + 0) * D_];
      float w1 = wo[(size_t)(k + 1) * D_];
      float w2 = wo[(size_t)(k + 2) * D_];
      float w3 = wo[(size_t)(k + 3) * D_];
      #pragma unroll
      for (int r = 0; r < 8; r++) {
        float4 a4 = *(const float4*)(sQ + r * DH_ + k);
        acc[r] = fmaf(a4.x, w0, fmaf(a4.y, w1, fmaf(a4.z, w2, fmaf(a4.w, w3, acc[r]))));
      }
    }
    float* Sb = S + ((size_t)(b * N_ + i0)) * D_ + tid;
    #pragma unroll
    for (int r = 0; r < 8; r++) atomicAdd(Sb + (size_t)r * D_, acc[r]);
  }
}

// ---------------- fused pair LN-mean + head (shuffle-free pair phase) ----------------
// grid = M, 256 threads
__global__ void pair_head_kernel(const float* __restrict__ projc, const float* __restrict__ projcT,
                                 const float* __restrict__ relc, const float* __restrict__ relcT,
                                 const float* __restrict__ lnw, const float* __restrict__ lnb,
                                 const float* __restrict__ x,
                                 const float* __restrict__ Wf1, const float* __restrict__ bWf1,
                                 const float* __restrict__ Wf2, const float* __restrict__ bWf2,
                                 float* __restrict__ frames, float* __restrict__ tx,
                                 float* __restrict__ ty, float* __restrict__ tz) {
  const int M = B_ * N_;
  int row = blockIdx.x;            // b*N + i
  int b = row / N_;
  int i = row % N_;
  int tid = threadIdx.x;           // 256 = 4 waves
  int lane = tid & 63;
  int wave = tid >> 6;
  __shared__ float svpi[PD_];
  __shared__ float sr[N_];         // rinv per j
  __shared__ float red[4][PD_];
  __shared__ float sfeat[320];
  __shared__ float fred[2][128];
  __shared__ float sg[128];
  __shared__ float sraw[9];

  if (tid < PD_) svpi[tid] = projc[row * PD_ + tid];
  if (tid < D_) sfeat[tid] = x[(size_t)row * D_ + tid];
  __syncthreads();

  // ---- pass A: rinv[j] via thread-per-j (coalesced transposed reads, no shuffles) ----
  {
    int jA = tid;                  // 0..255
    int raA = jA - i; raA = raA < -64 ? -64 : (raA > 64 ? 64 : raA); raA += 64;
    const float* pA = projcT + b * N_ + jA;
    const float* rA = relcT + raA;
    float s2A = 0.f;
    #pragma unroll 8
    for (int c = 0; c < PD_; c++) {
      float dA = svpi[c] + pA[(size_t)c * M] + rA[c * RT_];
      s2A = fmaf(dA, dA, s2A);
    }
    sr[jA] = rsqrtf(s2A * (1.0f / PD_) + 1e-5f);
    if (tid < 128) {
      int jB = tid + 256;          // 256..383
      int raB = jB - i; raB = raB < -64 ? -64 : (raB > 64 ? 64 : raB); raB += 64;
      const float* pB = projcT + b * N_ + jB;
      const float* rB = relcT + raB;
      float s2B = 0.f;
      #pragma unroll 8
      for (int c = 0; c < PD_; c++) {
        float dB = svpi[c] + pB[(size_t)c * M] + rB[c * RT_];
        s2B = fmaf(dB, dB, s2B);
      }
      sr[jB] = rsqrtf(s2B * (1.0f / PD_) + 1e-5f);
    }
  }
  __syncthreads();

  // ---- pass B: per-channel accumulation (row-major coalesced, no shuffles) ----
  {
    float vpl = svpi[lane];
    const float* pb = projc + (size_t)b * N_ * PD_;
    float acc = 0.0f;
    for (int j = wave * 2; j < N_; j += 8) {
      int ja = j, jb = j + 1;
      int ra = ja - i; ra = ra < -64 ? -64 : (ra > 64 ? 64 : ra); ra += 64;
      int rb = jb - i; rb = rb < -64 ? -64 : (rb > 64 ? 64 : rb); rb += 64;
      float da = vpl + pb[ja * PD_ + lane] + relc[ra * PD_ + lane];
      float db = vpl + pb[jb * PD_ + lane] + relc[rb * PD_ + lane];
      acc = fmaf(da, sr[ja], fmaf(db, sr[jb], acc));
    }
    red[wave][lane] = acc;
  }
  __syncthreads();
  if (wave == 0) {
    float s = red[0][lane] + red[1][lane] + red[2][lane] + red[3][lane];
    sfeat[D_ + lane] = lnb[lane] + s * lnw[lane] * (1.0f / N_);
  }
  __syncthreads();

  // ---- fc1 silu (320 -> 128), 2 k-chunks x 128 cols ----
  int kc = tid >> 7, c = tid & 127;
  int koff = kc * 160;
  const float* wp = Wf1 + (size_t)koff * 128 + c;
  const float* s0 = sfeat + koff;
  float a0 = 0.f, a1 = 0.f, a2 = 0.f, a3 = 0.f;
  for (int kk = 0; kk < 160; kk += 4) {
    a0 = fmaf(s0[kk],     wp[(size_t)kk * 128],       a0);
    a1 = fmaf(s0[kk + 1], wp[(size_t)(kk + 1) * 128], a1);
    a2 = fmaf(s0[kk + 2], wp[(size_t)(kk + 2) * 128], a2);
    a3 = fmaf(s0[kk + 3], wp[(size_t)(kk + 3) * 128], a3);
  }
  fred[kc][c] = (a0 + a1) + (a2 + a3);
  __syncthreads();
  if (tid < 128) {
    float g = fred[0][tid] + fred[1][tid] + bWf1[tid];
    sg[tid] = g / (1.0f + expf(-g));
  }
  __syncthreads();

  // ---- fc2 (128 -> 9), rot6d, frame write ----
  if (tid < 9) {
    float b0 = 0.f, b1v = 0.f;
    for (int kk = 0; kk < 128; kk += 2) {
      b0  = fmaf(sg[kk],     Wf2[(kk)     * 9 + tid], b0);
      b1v = fmaf(sg[kk + 1], Wf2[(kk + 1) * 9 + tid], b1v);
    }
    sraw[tid] = bWf2[tid] + b0 + b1v;
  }
  __syncthreads();
  if (tid == 0) {
    float a1x = sraw[0], a1y = sraw[1], a1z = sraw[2];
    float a2x = sraw[3], a2y = sraw[4], a2z = sraw[5];
    float n1 = sqrtf(a1x * a1x + a1y * a1y + a1z * a1z + 1e-8f);
    float b1x = a1x / n1, b1y = a1y / n1, b1z = a1z / n1;
    float dp = b1x * a2x + b1y * a2y + b1z * a2z;
    float px = a2x - dp * b1x, py = a2y - dp * b1y, pz = a2z - dp * b1z;
    float n2 = sqrtf(px * px + py * py + pz * pz + 1e-8f);
    float b2x = px / n2, b2y = py / n2, b2z = pz / n2;
    float b3x = b1y * b2z - b1z * b2y;
    float b3y = b1z * b2x - b1x * b2z;
    float b3z = b1x * b2y - b1y * b2x;
    float* f = frames + row * 16;
    f[0]  = b1x; f[1]  = b1y; f[2]  = b1z; f[3]  = sraw[6];
    f[4]  = b2x; f[5]  = b2y; f[6]  = b2z; f[7]  = sraw[7];
    f[8]  = b3x; f[9]  = b3y; f[10] = b3z; f[11] = sraw[8];
    f[12] = 0.0f; f[13] = 0.0f; f[14] = 0.0f; f[15] = 1.0f;
    tx[row] = sraw[6];
    ty[row] = sraw[7];
    tz[row] = sraw[8];
  }
}

// ---------------- output ----------------
__global__ void write_out_kernel(const float* __restrict__ frames, const float* __restrict__ x,
                                 float* __restrict__ out) {
  int i = blockIdx.x * 256 + threadIdx.x;
  const int nf = B_ * N_ * 16;
  const int total = nf + B_ * N_ * D_;
  if (i < nf) out[i] = frames[i];
  else if (i < total) out[i] = x[i - nf];
}

extern "C" void kernel_launch(void* const* d_in, const int* in_sizes, int n_in,
                              void* d_out, int out_size, void* d_ws, size_t ws_size,
                              hipStream_t stream) {
  const int*   tokens    = (const int*)  d_in[0];
  const float* tok_emb   = (const float*)d_in[1];
  const float* emb_ln_w  = (const float*)d_in[2];
  const float* emb_ln_b  = (const float*)d_in[3];
  const float* Wq        = (const float*)d_in[4];
  const float* Wk        = (const float*)d_in[5];
  const float* Wv        = (const float*)d_in[6];
  const float* Wo        = (const float*)d_in[7];
  const float* bo        = (const float*)d_in[8];
  const float* attn_ln_w = (const float*)d_in[9];
  const float* attn_ln_b = (const float*)d_in[10];
  const float* ff_ln_w   = (const float*)d_in[11];
  const float* ff_ln_b   = (const float*)d_in[12];
  const float* W1        = (const float*)d_in[13];
  const float* b1        = (const float*)d_in[14];
  const float* W2        = (const float*)d_in[15];
  const float* b2        = (const float*)d_in[16];
  const float* Wop       = (const float*)d_in[17];
  const float* bop       = (const float*)d_in[18];
  const float* relpos    = (const float*)d_in[19];
  const float* pair_ln_w = (const float*)d_in[20];
  const float* pair_ln_b = (const float*)d_in[21];
  const float* Wf1       = (const float*)d_in[22];
  const float* bWf1      = (const float*)d_in[23];
  const float* Wf2       = (const float*)d_in[24];
  const float* bWf2      = (const float*)d_in[25];

  const int M = B_ * N_;           // 768
  const int XE = M * D_;           // 196608
  float* ws     = (float*)d_ws;
  float* frames = ws;                      // 12288
  float* projc  = frames + M * 16;         // 49152
  float* projcT = projc  + M * PD_;        // 49152
  float* relc   = projcT + M * PD_;        // 8256 (pad 8320)
  float* relcT  = relc   + 8320;           // 64*132 = 8448
  float* tx     = relcT  + 8448;           // 768
  float* ty     = tx     + M;              // 768
  float* tz     = ty     + M;              // 768
  float* xA     = tz     + M;              // XE  (state ping)
  float* xB     = xA + XE;                 // XE  (state pong)
  float* q      = xB + XE;                 // XE
  float* kt     = q  + XE;                 // XE (K transposed [b,h,d,j])
  float* v      = kt + XE;                 // XE

  prologue_kernel<<<M, 256, 0, stream>>>(tokens, tok_emb, emb_ln_w, emb_ln_b, relpos,
                                         xA, frames, tx, ty, tz, relc, relcT, xB);
  qkv_kernel<<<(M / GR) * 12, 256, 0, stream>>>(xA, Wq, Wk, Wv, q, kt, v);

  for (int l = 0; l < L_; l++) {
    float* Sin  = (l & 1) ? xB : xA;       // holds x_l; attn accumulates ao@Wo into it
    float* Sout = (l & 1) ? xA : xB;       // pre-zeroed; ff accumulates new state
    attn_kernel<<<B_ * H_ * (N_ / IT), 256, 0, stream>>>(
        q, kt, v, tx, ty, tz, Wo + (size_t)l * D_ * D_, Sin);
    ff_fused_kernel<<<(M / GR) * 8, 256, 0, stream>>>(
        Sin, bo + l * D_,
        attn_ln_w + l * D_, attn_ln_b + l * D_,
        ff_ln_w + l * D_, ff_ln_b + l * D_,
        W1 + (size_t)l * D_ * 1024, b1 + l * 1024,
        W2 + (size_t)l * 1024 * D_, b2 + l * D_, Sout);
    if (l < L_ - 1) {
      int lq = l + 1;
      proj_qkv_kernel<<<M + (M / GR) * 12, 256, 0, stream>>>(
          Sout, Wop, bop, projc, projcT,
          Wq + (size_t)lq * D_ * D_, Wk + (size_t)lq * D_ * D_, Wv + (size_t)lq * D_ * D_,
          q, kt, v, Sin);
    } else {
      proj_qkv_kernel<<<M, 256, 0, stream>>>(Sout, Wop, bop, projc, projcT,
                                             Wq, Wk, Wv, q, kt, v, Sin);
    }
    pair_head_kernel<<<M, 256, 0, stream>>>(projc, projcT, relc, relcT, pair_ln_w, pair_ln_b,
                                            Sout, Wf1, bWf1, Wf2, bWf2, frames, tx, ty, tz);
  }

  // L_=8 layers: final state lands in xA
  const int total = B_ * N_ * 16 + B_ * N_ * D_;
  write_out_kernel<<<(total + 255) / 256, 256, 0, stream>>>(frames, xA, (float*)d_out);
}